// Round 12
// baseline (4229.745 us; speedup 1.0000x reference)
//
#include <hip/hip_runtime.h>
#include <hip/hip_bf16.h>

#define N_NODES 12288
#define D 256
#define NE 196608
#define TOPK 4
#define TM 128
#define TN 128
#define NSPLIT 16
#define CPS (N_NODES / NSPLIT)   // 768 cols per split
#define MAXDEG 256
// MEASURED (rounds 0-9): harness reads d_out as FLOAT32, identity layout:
// [ h 3145728 | top_idx 49152 | rows 49152 | top_vals 49152 ].

// ---------------- insert helpers (top-4, descending) ----------------
__device__ __forceinline__ void ins4(float v, int id, float tv[TOPK], int ti[TOPK]) {
  if (v > tv[3]) {
    tv[3] = v; ti[3] = id;
    if (tv[3] > tv[2]) {
      float a = tv[2]; tv[2] = tv[3]; tv[3] = a; int b = ti[2]; ti[2] = ti[3]; ti[3] = b;
      if (tv[2] > tv[1]) {
        float a2 = tv[1]; tv[1] = tv[2]; tv[2] = a2; int b2 = ti[1]; ti[1] = ti[2]; ti[2] = b2;
        if (tv[1] > tv[0]) {
          float a3 = tv[0]; tv[0] = tv[1]; tv[1] = a3; int b3 = ti[0]; ti[0] = ti[1]; ti[1] = b3;
        }
      }
    }
  }
}

__device__ __forceinline__ void ins4tie(float v, int id, float tv[TOPK], int ti[TOPK]) {
  if ((v > tv[3]) || (v == tv[3] && id < ti[3])) {
    tv[3] = v; ti[3] = id;
    if ((tv[3] > tv[2]) || (tv[3] == tv[2] && ti[3] < ti[2])) {
      float a = tv[2]; tv[2] = tv[3]; tv[3] = a; int b = ti[2]; ti[2] = ti[3]; ti[3] = b;
      if ((tv[2] > tv[1]) || (tv[2] == tv[1] && ti[2] < ti[1])) {
        float a2 = tv[1]; tv[1] = tv[2]; tv[2] = a2; int b2 = ti[1]; ti[1] = ti[2]; ti[2] = b2;
        if ((tv[1] > tv[0]) || (tv[1] == tv[0] && ti[1] < ti[0])) {
          float a3 = tv[0]; tv[0] = tv[1]; tv[1] = a3; int b3 = ti[0]; ti[0] = ti[1]; ti[1] = b3;
        }
      }
    }
  }
}

// ---------------- K1: XW = x @ W ----------------
__global__ __launch_bounds__(256) void k_xw(const float* __restrict__ X,
                                            const float* __restrict__ W,
                                            float* __restrict__ XW) {
  __shared__ float sA[16][65];
  __shared__ float sB[16][65];
  const int tid = threadIdx.x;
  const int ty = tid >> 4, tx = tid & 15;
  const int by = blockIdx.x, bx = blockIdx.y;
  float acc[4][4] = {};
  for (int kk = 0; kk < D; kk += 16) {
    {
      int m = tid >> 2;
      int kq = (tid & 3) << 2;
      const float4 av = *(const float4*)&X[(size_t)(by * 64 + m) * D + kk + kq];
      sA[kq + 0][m] = av.x; sA[kq + 1][m] = av.y; sA[kq + 2][m] = av.z; sA[kq + 3][m] = av.w;
    }
    {
      int r = tid >> 4;
      int c = (tid & 15) << 2;
      const float4 bv = *(const float4*)&W[(size_t)(kk + r) * D + bx * 64 + c];
      sB[r][c + 0] = bv.x; sB[r][c + 1] = bv.y; sB[r][c + 2] = bv.z; sB[r][c + 3] = bv.w;
    }
    __syncthreads();
#pragma unroll
    for (int k = 0; k < 16; ++k) {
      float a[4], b[4];
#pragma unroll
      for (int i = 0; i < 4; i++) a[i] = sA[k][ty + 16 * i];
#pragma unroll
      for (int j = 0; j < 4; j++) b[j] = sB[k][tx + 16 * j];
#pragma unroll
      for (int i = 0; i < 4; i++)
#pragma unroll
        for (int j = 0; j < 4; j++) acc[i][j] = fmaf(a[i], b[j], acc[i][j]);
    }
    __syncthreads();
  }
#pragma unroll
  for (int i = 0; i < 4; i++)
#pragma unroll
    for (int j = 0; j < 4; j++)
      XW[(size_t)(by * 64 + ty + 16 * i) * D + bx * 64 + tx + 16 * j] = acc[i][j];
}

// ---------------- K2: in-degree histogram ----------------
__global__ void k_deg(const int* __restrict__ row, int* __restrict__ deg) {
  int e = blockIdx.x * blockDim.x + threadIdx.x;
  if (e < NE) {
    unsigned r = (unsigned)row[e];
    if (r < N_NODES) atomicAdd(&deg[r], 1);
  }
}

// ---------------- K3: exclusive scan + dinv ----------------
__global__ __launch_bounds__(256) void k_scan(const int* __restrict__ deg,
                                              int* __restrict__ row_start,
                                              float* __restrict__ dinv) {
  __shared__ int part[256];
  const int tid = threadIdx.x;
  const int L = N_NODES / 256;  // 48
  const int base = tid * L;
  int s = 0;
  for (int i = 0; i < L; i++) s += deg[base + i];
  part[tid] = s;
  __syncthreads();
  for (int off = 1; off < 256; off <<= 1) {
    int v = (tid >= off) ? part[tid - off] : 0;
    __syncthreads();
    part[tid] += v;
    __syncthreads();
  }
  int run = part[tid] - s;
  for (int i = 0; i < L; i++) {
    int d = deg[base + i];
    row_start[base + i] = run;
    dinv[base + i] = 1.0f / sqrtf((float)(d + 1));
    run += d;
  }
}

// ---------------- K4: CSR fill ----------------
__global__ void k_fill(const int* __restrict__ row, const int* __restrict__ col,
                       const int* __restrict__ row_start, int* __restrict__ cursor,
                       int* __restrict__ ecol, int* __restrict__ eeid) {
  int e = blockIdx.x * blockDim.x + threadIdx.x;
  if (e >= NE) return;
  unsigned r = (unsigned)row[e];
  if (r >= N_NODES) return;
  int p = atomicAdd(&cursor[r], 1);
  int slot = row_start[r] + p;
  if ((unsigned)slot >= NE) return;
  unsigned c = (unsigned)col[e];
  if (c >= N_NODES) c = 0;
  ecol[slot] = (int)c;
  eeid[slot] = e;
}

// ---------------- K5: aggregation (eid-sorted -> deterministic); h -> d_out ------
__global__ __launch_bounds__(256) void k_agg(const float* __restrict__ XW,
                                             const float* __restrict__ bias,
                                             const int* __restrict__ deg,
                                             const int* __restrict__ row_start,
                                             const int* __restrict__ ecol,
                                             const int* __restrict__ eeid,
                                             const float* __restrict__ dinv,
                                             float* __restrict__ h_out,
                                             float* __restrict__ sq) {
  __shared__ int sc[MAXDEG];
  __shared__ int se[MAXDEG];
  __shared__ float snorm[MAXDEG];
  __shared__ float red[256];
  const int i = blockIdx.x;
  const int tid = threadIdx.x;
  int cnt = deg[i];
  if (cnt > MAXDEG) cnt = MAXDEG;
  if (cnt < 0) cnt = 0;
  const int st = row_start[i];
  for (int t = tid; t < cnt; t += 256) {
    unsigned cc = (unsigned)ecol[st + t];
    sc[t] = (cc < N_NODES) ? (int)cc : 0;
    se[t] = eeid[st + t];
  }
  __syncthreads();
  if (tid == 0) {  // insertion sort by original edge id
    for (int a = 1; a < cnt; ++a) {
      int ce = se[a], cc = sc[a];
      int bp = a - 1;
      while (bp >= 0 && se[bp] > ce) { se[bp + 1] = se[bp]; sc[bp + 1] = sc[bp]; --bp; }
      se[bp + 1] = ce; sc[bp + 1] = cc;
    }
  }
  __syncthreads();
  const float di = dinv[i];
  for (int t = tid; t < cnt; t += 256) snorm[t] = __fmul_rn(di, dinv[sc[t]]);
  __syncthreads();
  float acc = 0.0f;
  for (int t = 0; t < cnt; ++t) {
    float v = XW[(size_t)sc[t] * D + tid];
    acc = __fadd_rn(acc, __fmul_rn(v, snorm[t]));
  }
  acc = __fadd_rn(acc, __fmul_rn(XW[(size_t)i * D + tid], __fmul_rn(di, di)));  // self loop last
  acc = __fadd_rn(acc, bias[tid]);
  h_out[(size_t)i * D + tid] = acc;
  red[tid] = __fmul_rn(acc, acc);
  __syncthreads();
  for (int off = 128; off > 0; off >>= 1) {
    if (tid < off) red[tid] = __fadd_rn(red[tid], red[tid + off]);
    __syncthreads();
  }
  if (tid == 0) sq[i] = red[0];
}

// ---------------- K6 v3: fused d2 + gumbel + top-4 (8x8 register microtile) ------
// Round-11 diagnosis: LDS-BW-bound (193 GB LDS reads at the ~66 TB/s ceiling,
// VALUBusy 37%). Fix: 8x8 f4-microtile -> 0.5 B/FLOP (38.6 GB), FMA:ds = 16:1,
// padded stride-9 LDS (conflict-free, induction-friendly addresses, no XOR).
// 1 block/CU, launch_bounds(256,1) -> 512 VGPR cap (acc[8][8] f4 = 256 regs).
// Accumulation order & lq op-order IDENTICAL to the passing round-11 kernel.
__global__ __launch_bounds__(256, 1) void k_fused(const float* __restrict__ h,
                                                  const float* __restrict__ sq,
                                                  const float* __restrict__ q,
                                                  const float* __restrict__ tempP,
                                                  float* __restrict__ cval,
                                                  int* __restrict__ cidx) {
  __shared__ float4 sA4[TM * 9];  // [row][kf4 0..7], stride 9 f4 (pad) = 18 KB
  __shared__ float4 sB4[TN * 9];  // same, 18 KB
  const int tid = threadIdx.x;
  const int tx = tid & 15;        // col group
  const int ty = tid >> 4;        // row group
  const int row0 = blockIdx.x * TM;
  const int split = blockIdx.y;
  const int c0 = split * CPS;
  const float T = tempP[0];
  const float4* hf4 = (const float4*)h;

  float sqr[8];
#pragma unroll
  for (int i = 0; i < 8; ++i) sqr[i] = sq[row0 + ty + 16 * i];

  float tv[8][TOPK];
  int ti[8][TOPK];
#pragma unroll
  for (int i = 0; i < 8; ++i)
#pragma unroll
    for (int k = 0; k < TOPK; ++k) { tv[i][k] = -3.0e38f; ti[i][k] = 0; }

  for (int ct = c0; ct < c0 + CPS; ct += TN) {  // 6 col-tiles
    float4 acc[8][8];
#pragma unroll
    for (int i = 0; i < 8; ++i)
#pragma unroll
      for (int j = 0; j < 8; ++j) acc[i][j] = make_float4(0.f, 0.f, 0.f, 0.f);

    for (int kc = 0; kc < 64; kc += 8) {  // 8 k-chunks of 8 float4 (32 dims)
      __syncthreads();  // protect previous chunk's reads
#pragma unroll
      for (int t = 0; t < 4; ++t) {
        int fi = t * 256 + tid;       // 0..1023
        int r = fi >> 3, k = fi & 7;
        sA4[r * 9 + k] = hf4[(size_t)(row0 + r) * 64 + kc + k];
        sB4[r * 9 + k] = hf4[(size_t)(ct + r) * 64 + kc + k];
      }
      __syncthreads();
#pragma unroll
      for (int kf = 0; kf < 8; ++kf) {
        float4 a[8], b[8];
#pragma unroll
        for (int i = 0; i < 8; ++i) a[i] = sA4[(ty + 16 * i) * 9 + kf];
#pragma unroll
        for (int j = 0; j < 8; ++j) b[j] = sB4[(tx + 16 * j) * 9 + kf];
#pragma unroll
        for (int i = 0; i < 8; ++i)
#pragma unroll
          for (int j = 0; j < 8; ++j) {
            acc[i][j].x = fmaf(a[i].x, b[j].x, acc[i][j].x);
            acc[i][j].y = fmaf(a[i].y, b[j].y, acc[i][j].y);
            acc[i][j].z = fmaf(a[i].z, b[j].z, acc[i][j].z);
            acc[i][j].w = fmaf(a[i].w, b[j].w, acc[i][j].w);
          }
      }
    }

    // epilogue: lq + top-4 insert (same op order as round 11; ascending c)
    float sqc[8];
#pragma unroll
    for (int j = 0; j < 8; ++j) sqc[j] = sq[ct + tx + 16 * j];
#pragma unroll
    for (int i = 0; i < 8; ++i) {
      const float* qr = q + (size_t)(row0 + ty + 16 * i) * N_NODES;
#pragma unroll
      for (int j = 0; j < 8; ++j) {
        const int c = ct + tx + 16 * j;
        float dot = __fadd_rn(__fadd_rn(acc[i][j].x, acc[i][j].y),
                              __fadd_rn(acc[i][j].z, acc[i][j].w));
        float s2 = __fadd_rn(sqr[i], sqc[j]);
        float d2 = fmaxf(__fsub_rn(s2, __fmul_rn(2.0f, dot)), 0.0f);
        float lp = -__fmul_rn(T, d2);
        float gg = logf(-logf(__fadd_rn(qr[c], 1e-8f)));
        ins4(__fsub_rn(lp, gg), c, tv[i], ti[i]);
      }
    }
  }

  // butterfly merge across the 16 col-lanes (same ty), width-16
#pragma unroll
  for (int i = 0; i < 8; ++i) {
#pragma unroll
    for (int m = 1; m < 16; m <<= 1) {
      float ov[TOPK]; int oi[TOPK];
#pragma unroll
      for (int k = 0; k < TOPK; ++k) {
        ov[k] = __shfl_xor(tv[i][k], m, 16);
        oi[k] = __shfl_xor(ti[i][k], m, 16);
      }
#pragma unroll
      for (int k = 0; k < TOPK; ++k) ins4tie(ov[k], oi[k], tv[i], ti[i]);
    }
  }
  if (tx == 0) {
#pragma unroll
    for (int i = 0; i < 8; ++i) {
      int r = row0 + ty + 16 * i;
#pragma unroll
      for (int k = 0; k < TOPK; ++k) {
        cval[((size_t)r * NSPLIT + split) * TOPK + k] = tv[i][k];
        cidx[((size_t)r * NSPLIT + split) * TOPK + k] = ti[i][k];
      }
    }
  }
}

// ---------------- K7: merge splits, write edges + top_vals as FLOAT32 ----------
__global__ __launch_bounds__(256) void k_merge(const float* __restrict__ cval,
                                               const int* __restrict__ cidx,
                                               float* __restrict__ out_idx,
                                               float* __restrict__ out_rows,
                                               float* __restrict__ out_vals) {
  int r = blockIdx.x * blockDim.x + threadIdx.x;
  if (r >= N_NODES) return;
  float bv[TOPK];
  int bi[TOPK];
#pragma unroll
  for (int k = 0; k < TOPK; k++) { bv[k] = -3.0e38f; bi[k] = 0; }
  for (int t = 0; t < NSPLIT * TOPK; t++)
    ins4tie(cval[(size_t)r * NSPLIT * TOPK + t], cidx[(size_t)r * NSPLIT * TOPK + t], bv, bi);
#pragma unroll
  for (int k = 0; k < TOPK; k++) {
    out_idx[r * TOPK + k] = (float)bi[k];
    out_rows[r * TOPK + k] = (float)r;
    out_vals[r * TOPK + k] = bv[k];
  }
}

// ---------------- launcher ----------------
extern "C" void kernel_launch(void* const* d_in, const int* in_sizes, int n_in,
                              void* d_out, int out_size, void* d_ws, size_t ws_size,
                              hipStream_t stream) {
  const float* x = nullptr;     // 3145728
  const float* W = nullptr;     // 65536
  const float* b = nullptr;     // 256
  const float* temp = nullptr;  // 1
  const float* q = nullptr;     // 150994944
  const int* ei = nullptr;      // 393216
  for (int i = 0; i < n_in; ++i) {
    switch (in_sizes[i]) {
      case 3145728:   x = (const float*)d_in[i]; break;
      case 65536:     W = (const float*)d_in[i]; break;
      case 256:       b = (const float*)d_in[i]; break;
      case 1:         temp = (const float*)d_in[i]; break;
      case 150994944: q = (const float*)d_in[i]; break;
      case 393216:    ei = (const int*)d_in[i]; break;
      default: break;
    }
  }
  if (!x || !W || !b || !temp || !q || !ei) return;

  float* out = (float*)d_out;
  float* out_h = out;                                  // [0, 3145728)
  float* out_idx = out + (size_t)N_NODES * D;          // [3145728, 3194880)
  float* out_rows = out_idx + (size_t)N_NODES * TOPK;  // [3194880, 3244032)
  float* out_vals = out_rows + (size_t)N_NODES * TOPK; // [3244032, 3293184)

  char* ws = (char*)d_ws;
  size_t off = 0;
  auto alloc = [&](size_t bytes) {
    char* p = ws + off;
    off += (bytes + 255) & ~(size_t)255;
    return p;
  };
  float* XW = (float*)alloc((size_t)N_NODES * D * 4);
  int* deg = (int*)alloc((size_t)N_NODES * 4);
  int* rs = (int*)alloc((size_t)N_NODES * 4);
  int* cur = (int*)alloc((size_t)N_NODES * 4);
  float* dinv = (float*)alloc((size_t)N_NODES * 4);
  float* sq = (float*)alloc((size_t)N_NODES * 4);
  int* ecol = (int*)alloc((size_t)NE * 4);
  int* eeid = (int*)alloc((size_t)NE * 4);
  float* cval = (float*)alloc((size_t)N_NODES * NSPLIT * TOPK * 4);
  int* cidx = (int*)alloc((size_t)N_NODES * NSPLIT * TOPK * 4);
  if (off > ws_size) return;

  hipMemsetAsync(deg, 0, (size_t)N_NODES * 4, stream);
  hipMemsetAsync(cur, 0, (size_t)N_NODES * 4, stream);

  k_xw<<<dim3(N_NODES / 64, D / 64), 256, 0, stream>>>(x, W, XW);
  k_deg<<<NE / 256, 256, 0, stream>>>(ei, deg);
  k_scan<<<1, 256, 0, stream>>>(deg, rs, dinv);
  k_fill<<<NE / 256, 256, 0, stream>>>(ei, ei + NE, rs, cur, ecol, eeid);
  k_agg<<<N_NODES, 256, 0, stream>>>(XW, b, deg, rs, ecol, eeid, dinv, out_h, sq);
  k_fused<<<dim3(N_NODES / TM, NSPLIT), 256, 0, stream>>>(out_h, sq, q, temp, cval, cidx);
  k_merge<<<N_NODES / 256, 256, 0, stream>>>(cval, cidx, out_idx, out_rows, out_vals);
}

// Round 13
// 2720.310 us; speedup vs baseline: 1.5549x; 1.5549x over previous
//
#include <hip/hip_runtime.h>
#include <hip/hip_bf16.h>

#define N_NODES 12288
#define D 256
#define NE 196608
#define TOPK 4
#define TM 128
#define TN 128
#define NSPLIT 16
#define CPS (N_NODES / NSPLIT)   // 768 cols per split
#define MAXDEG 256
// MEASURED (rounds 0-9): harness reads d_out as FLOAT32, identity layout:
// [ h 3145728 | top_idx 49152 | rows 49152 | top_vals 49152 ].

// ---------------- insert helpers (top-4, descending) ----------------
__device__ __forceinline__ void ins4(float v, int id, float tv[TOPK], int ti[TOPK]) {
  if (v > tv[3]) {
    tv[3] = v; ti[3] = id;
    if (tv[3] > tv[2]) {
      float a = tv[2]; tv[2] = tv[3]; tv[3] = a; int b = ti[2]; ti[2] = ti[3]; ti[3] = b;
      if (tv[2] > tv[1]) {
        float a2 = tv[1]; tv[1] = tv[2]; tv[2] = a2; int b2 = ti[1]; ti[1] = ti[2]; ti[2] = b2;
        if (tv[1] > tv[0]) {
          float a3 = tv[0]; tv[0] = tv[1]; tv[1] = a3; int b3 = ti[0]; ti[0] = ti[1]; ti[1] = b3;
        }
      }
    }
  }
}

__device__ __forceinline__ void ins4tie(float v, int id, float tv[TOPK], int ti[TOPK]) {
  if ((v > tv[3]) || (v == tv[3] && id < ti[3])) {
    tv[3] = v; ti[3] = id;
    if ((tv[3] > tv[2]) || (tv[3] == tv[2] && ti[3] < ti[2])) {
      float a = tv[2]; tv[2] = tv[3]; tv[3] = a; int b = ti[2]; ti[2] = ti[3]; ti[3] = b;
      if ((tv[2] > tv[1]) || (tv[2] == tv[1] && ti[2] < ti[1])) {
        float a2 = tv[1]; tv[1] = tv[2]; tv[2] = a2; int b2 = ti[1]; ti[1] = ti[2]; ti[2] = b2;
        if ((tv[1] > tv[0]) || (tv[1] == tv[0] && ti[1] < ti[0])) {
          float a3 = tv[0]; tv[0] = tv[1]; tv[1] = a3; int b3 = ti[0]; ti[0] = ti[1]; ti[1] = b3;
        }
      }
    }
  }
}

// ---------------- K1: XW = x @ W ----------------
__global__ __launch_bounds__(256) void k_xw(const float* __restrict__ X,
                                            const float* __restrict__ W,
                                            float* __restrict__ XW) {
  __shared__ float sA[16][65];
  __shared__ float sB[16][65];
  const int tid = threadIdx.x;
  const int ty = tid >> 4, tx = tid & 15;
  const int by = blockIdx.x, bx = blockIdx.y;
  float acc[4][4] = {};
  for (int kk = 0; kk < D; kk += 16) {
    {
      int m = tid >> 2;
      int kq = (tid & 3) << 2;
      const float4 av = *(const float4*)&X[(size_t)(by * 64 + m) * D + kk + kq];
      sA[kq + 0][m] = av.x; sA[kq + 1][m] = av.y; sA[kq + 2][m] = av.z; sA[kq + 3][m] = av.w;
    }
    {
      int r = tid >> 4;
      int c = (tid & 15) << 2;
      const float4 bv = *(const float4*)&W[(size_t)(kk + r) * D + bx * 64 + c];
      sB[r][c + 0] = bv.x; sB[r][c + 1] = bv.y; sB[r][c + 2] = bv.z; sB[r][c + 3] = bv.w;
    }
    __syncthreads();
#pragma unroll
    for (int k = 0; k < 16; ++k) {
      float a[4], b[4];
#pragma unroll
      for (int i = 0; i < 4; i++) a[i] = sA[k][ty + 16 * i];
#pragma unroll
      for (int j = 0; j < 4; j++) b[j] = sB[k][tx + 16 * j];
#pragma unroll
      for (int i = 0; i < 4; i++)
#pragma unroll
        for (int j = 0; j < 4; j++) acc[i][j] = fmaf(a[i], b[j], acc[i][j]);
    }
    __syncthreads();
  }
#pragma unroll
  for (int i = 0; i < 4; i++)
#pragma unroll
    for (int j = 0; j < 4; j++)
      XW[(size_t)(by * 64 + ty + 16 * i) * D + bx * 64 + tx + 16 * j] = acc[i][j];
}

// ---------------- K2: in-degree histogram ----------------
__global__ void k_deg(const int* __restrict__ row, int* __restrict__ deg) {
  int e = blockIdx.x * blockDim.x + threadIdx.x;
  if (e < NE) {
    unsigned r = (unsigned)row[e];
    if (r < N_NODES) atomicAdd(&deg[r], 1);
  }
}

// ---------------- K3: exclusive scan + dinv ----------------
__global__ __launch_bounds__(256) void k_scan(const int* __restrict__ deg,
                                              int* __restrict__ row_start,
                                              float* __restrict__ dinv) {
  __shared__ int part[256];
  const int tid = threadIdx.x;
  const int L = N_NODES / 256;  // 48
  const int base = tid * L;
  int s = 0;
  for (int i = 0; i < L; i++) s += deg[base + i];
  part[tid] = s;
  __syncthreads();
  for (int off = 1; off < 256; off <<= 1) {
    int v = (tid >= off) ? part[tid - off] : 0;
    __syncthreads();
    part[tid] += v;
    __syncthreads();
  }
  int run = part[tid] - s;
  for (int i = 0; i < L; i++) {
    int d = deg[base + i];
    row_start[base + i] = run;
    dinv[base + i] = 1.0f / sqrtf((float)(d + 1));
    run += d;
  }
}

// ---------------- K4: CSR fill ----------------
__global__ void k_fill(const int* __restrict__ row, const int* __restrict__ col,
                       const int* __restrict__ row_start, int* __restrict__ cursor,
                       int* __restrict__ ecol, int* __restrict__ eeid) {
  int e = blockIdx.x * blockDim.x + threadIdx.x;
  if (e >= NE) return;
  unsigned r = (unsigned)row[e];
  if (r >= N_NODES) return;
  int p = atomicAdd(&cursor[r], 1);
  int slot = row_start[r] + p;
  if ((unsigned)slot >= NE) return;
  unsigned c = (unsigned)col[e];
  if (c >= N_NODES) c = 0;
  ecol[slot] = (int)c;
  eeid[slot] = e;
}

// ---------------- K5: aggregation (eid-sorted -> deterministic); h -> d_out ------
__global__ __launch_bounds__(256) void k_agg(const float* __restrict__ XW,
                                             const float* __restrict__ bias,
                                             const int* __restrict__ deg,
                                             const int* __restrict__ row_start,
                                             const int* __restrict__ ecol,
                                             const int* __restrict__ eeid,
                                             const float* __restrict__ dinv,
                                             float* __restrict__ h_out,
                                             float* __restrict__ sq) {
  __shared__ int sc[MAXDEG];
  __shared__ int se[MAXDEG];
  __shared__ float snorm[MAXDEG];
  __shared__ float red[256];
  const int i = blockIdx.x;
  const int tid = threadIdx.x;
  int cnt = deg[i];
  if (cnt > MAXDEG) cnt = MAXDEG;
  if (cnt < 0) cnt = 0;
  const int st = row_start[i];
  for (int t = tid; t < cnt; t += 256) {
    unsigned cc = (unsigned)ecol[st + t];
    sc[t] = (cc < N_NODES) ? (int)cc : 0;
    se[t] = eeid[st + t];
  }
  __syncthreads();
  if (tid == 0) {  // insertion sort by original edge id
    for (int a = 1; a < cnt; ++a) {
      int ce = se[a], cc = sc[a];
      int bp = a - 1;
      while (bp >= 0 && se[bp] > ce) { se[bp + 1] = se[bp]; sc[bp + 1] = sc[bp]; --bp; }
      se[bp + 1] = ce; sc[bp + 1] = cc;
    }
  }
  __syncthreads();
  const float di = dinv[i];
  for (int t = tid; t < cnt; t += 256) snorm[t] = __fmul_rn(di, dinv[sc[t]]);
  __syncthreads();
  float acc = 0.0f;
  for (int t = 0; t < cnt; ++t) {
    float v = XW[(size_t)sc[t] * D + tid];
    acc = __fadd_rn(acc, __fmul_rn(v, snorm[t]));
  }
  acc = __fadd_rn(acc, __fmul_rn(XW[(size_t)i * D + tid], __fmul_rn(di, di)));  // self loop last
  acc = __fadd_rn(acc, bias[tid]);
  h_out[(size_t)i * D + tid] = acc;
  red[tid] = __fmul_rn(acc, acc);
  __syncthreads();
  for (int off = 128; off > 0; off >>= 1) {
    if (tid < off) red[tid] = __fadd_rn(red[tid], red[tid + off]);
    __syncthreads();
  }
  if (tid == 0) sq[i] = red[0];
}

// ---------------- K6 v4: fused d2 + gumbel + top-4 (8x8 SCALAR-acc microtile) ----
// Round-12 diagnosis: acc[8][8] float4 = 256 VGPRs alone -> allocator at the
// 256-arch-VGPR cap -> scratch shuffling (VALUBusy 34%, 4.3 ms). v4 keeps the
// 8x8 tile (FMA:ds_read = 16:1, FMA-issue-bound) but accumulates SCALAR dots:
// acc 64 + a/b 64 + tv/ti 64 + misc ~ 230 VGPR -> no spill.
// (fp32 accumulation-order change vs r11/r12: error ~1e-5 << Gumbel rank gaps.)
__global__ __launch_bounds__(256, 1) void k_fused(const float* __restrict__ h,
                                                  const float* __restrict__ sq,
                                                  const float* __restrict__ q,
                                                  const float* __restrict__ tempP,
                                                  float* __restrict__ cval,
                                                  int* __restrict__ cidx) {
  __shared__ float4 sA4[TM * 9];  // [row][kf 0..7], stride 9 f4 (pad) = 18 KB
  __shared__ float4 sB4[TN * 9];  // 18 KB
  const int tid = threadIdx.x;
  const int tx = tid & 15;
  const int ty = tid >> 4;
  const int row0 = blockIdx.x * TM;
  const int split = blockIdx.y;
  const int c0 = split * CPS;
  const float T = tempP[0];
  const float4* hf4 = (const float4*)h;

  float sqr[8];
#pragma unroll
  for (int i = 0; i < 8; ++i) sqr[i] = sq[row0 + ty + 16 * i];

  float tv[8][TOPK];
  int ti[8][TOPK];
#pragma unroll
  for (int i = 0; i < 8; ++i)
#pragma unroll
    for (int k = 0; k < TOPK; ++k) { tv[i][k] = -3.0e38f; ti[i][k] = 0; }

  for (int ct = c0; ct < c0 + CPS; ct += TN) {  // 6 col-tiles
    float acc[8][8];
#pragma unroll
    for (int i = 0; i < 8; ++i)
#pragma unroll
      for (int j = 0; j < 8; ++j) acc[i][j] = 0.0f;

    for (int kc = 0; kc < 64; kc += 8) {  // 8 k-chunks of 8 float4 (32 dims)
      __syncthreads();
#pragma unroll
      for (int t = 0; t < 4; ++t) {
        int fi = t * 256 + tid;       // 0..1023
        int r = fi >> 3, k = fi & 7;
        sA4[r * 9 + k] = hf4[(size_t)(row0 + r) * 64 + kc + k];
        sB4[r * 9 + k] = hf4[(size_t)(ct + r) * 64 + kc + k];
      }
      __syncthreads();
#pragma unroll
      for (int kf = 0; kf < 8; ++kf) {
        float4 a[8], b[8];
#pragma unroll
        for (int i = 0; i < 8; ++i) a[i] = sA4[(ty + 16 * i) * 9 + kf];
#pragma unroll
        for (int j = 0; j < 8; ++j) b[j] = sB4[(tx + 16 * j) * 9 + kf];
#pragma unroll
        for (int i = 0; i < 8; ++i)
#pragma unroll
          for (int j = 0; j < 8; ++j) {
            float s = acc[i][j];
            s = fmaf(a[i].x, b[j].x, s);
            s = fmaf(a[i].y, b[j].y, s);
            s = fmaf(a[i].z, b[j].z, s);
            s = fmaf(a[i].w, b[j].w, s);
            acc[i][j] = s;
          }
      }
    }

    // epilogue: lq + top-4 insert (ascending c within each thread)
    float sqc[8];
#pragma unroll
    for (int j = 0; j < 8; ++j) sqc[j] = sq[ct + tx + 16 * j];
#pragma unroll
    for (int i = 0; i < 8; ++i) {
      const float* qr = q + (size_t)(row0 + ty + 16 * i) * N_NODES;
#pragma unroll
      for (int j = 0; j < 8; ++j) {
        const int c = ct + tx + 16 * j;
        float s2 = __fadd_rn(sqr[i], sqc[j]);
        float d2 = fmaxf(__fsub_rn(s2, __fmul_rn(2.0f, acc[i][j])), 0.0f);
        float lp = -__fmul_rn(T, d2);
        float gg = logf(-logf(__fadd_rn(qr[c], 1e-8f)));
        ins4(__fsub_rn(lp, gg), c, tv[i], ti[i]);
      }
    }
  }

  // butterfly merge across the 16 col-lanes (same ty), width-16
#pragma unroll
  for (int i = 0; i < 8; ++i) {
#pragma unroll
    for (int m = 1; m < 16; m <<= 1) {
      float ov[TOPK]; int oi[TOPK];
#pragma unroll
      for (int k = 0; k < TOPK; ++k) {
        ov[k] = __shfl_xor(tv[i][k], m, 16);
        oi[k] = __shfl_xor(ti[i][k], m, 16);
      }
#pragma unroll
      for (int k = 0; k < TOPK; ++k) ins4tie(ov[k], oi[k], tv[i], ti[i]);
    }
  }
  if (tx == 0) {
#pragma unroll
    for (int i = 0; i < 8; ++i) {
      int r = row0 + ty + 16 * i;
#pragma unroll
      for (int k = 0; k < TOPK; ++k) {
        cval[((size_t)r * NSPLIT + split) * TOPK + k] = tv[i][k];
        cidx[((size_t)r * NSPLIT + split) * TOPK + k] = ti[i][k];
      }
    }
  }
}

// ---------------- K7: merge splits, write edges + top_vals as FLOAT32 ----------
__global__ __launch_bounds__(256) void k_merge(const float* __restrict__ cval,
                                               const int* __restrict__ cidx,
                                               float* __restrict__ out_idx,
                                               float* __restrict__ out_rows,
                                               float* __restrict__ out_vals) {
  int r = blockIdx.x * blockDim.x + threadIdx.x;
  if (r >= N_NODES) return;
  float bv[TOPK];
  int bi[TOPK];
#pragma unroll
  for (int k = 0; k < TOPK; k++) { bv[k] = -3.0e38f; bi[k] = 0; }
  for (int t = 0; t < NSPLIT * TOPK; t++)
    ins4tie(cval[(size_t)r * NSPLIT * TOPK + t], cidx[(size_t)r * NSPLIT * TOPK + t], bv, bi);
#pragma unroll
  for (int k = 0; k < TOPK; k++) {
    out_idx[r * TOPK + k] = (float)bi[k];
    out_rows[r * TOPK + k] = (float)r;
    out_vals[r * TOPK + k] = bv[k];
  }
}

// ---------------- launcher ----------------
extern "C" void kernel_launch(void* const* d_in, const int* in_sizes, int n_in,
                              void* d_out, int out_size, void* d_ws, size_t ws_size,
                              hipStream_t stream) {
  const float* x = nullptr;     // 3145728
  const float* W = nullptr;     // 65536
  const float* b = nullptr;     // 256
  const float* temp = nullptr;  // 1
  const float* q = nullptr;     // 150994944
  const int* ei = nullptr;      // 393216
  for (int i = 0; i < n_in; ++i) {
    switch (in_sizes[i]) {
      case 3145728:   x = (const float*)d_in[i]; break;
      case 65536:     W = (const float*)d_in[i]; break;
      case 256:       b = (const float*)d_in[i]; break;
      case 1:         temp = (const float*)d_in[i]; break;
      case 150994944: q = (const float*)d_in[i]; break;
      case 393216:    ei = (const int*)d_in[i]; break;
      default: break;
    }
  }
  if (!x || !W || !b || !temp || !q || !ei) return;

  float* out = (float*)d_out;
  float* out_h = out;                                  // [0, 3145728)
  float* out_idx = out + (size_t)N_NODES * D;          // [3145728, 3194880)
  float* out_rows = out_idx + (size_t)N_NODES * TOPK;  // [3194880, 3244032)
  float* out_vals = out_rows + (size_t)N_NODES * TOPK; // [3244032, 3293184)

  char* ws = (char*)d_ws;
  size_t off = 0;
  auto alloc = [&](size_t bytes) {
    char* p = ws + off;
    off += (bytes + 255) & ~(size_t)255;
    return p;
  };
  float* XW = (float*)alloc((size_t)N_NODES * D * 4);
  int* deg = (int*)alloc((size_t)N_NODES * 4);
  int* rs = (int*)alloc((size_t)N_NODES * 4);
  int* cur = (int*)alloc((size_t)N_NODES * 4);
  float* dinv = (float*)alloc((size_t)N_NODES * 4);
  float* sq = (float*)alloc((size_t)N_NODES * 4);
  int* ecol = (int*)alloc((size_t)NE * 4);
  int* eeid = (int*)alloc((size_t)NE * 4);
  float* cval = (float*)alloc((size_t)N_NODES * NSPLIT * TOPK * 4);
  int* cidx = (int*)alloc((size_t)N_NODES * NSPLIT * TOPK * 4);
  if (off > ws_size) return;

  hipMemsetAsync(deg, 0, (size_t)N_NODES * 4, stream);
  hipMemsetAsync(cur, 0, (size_t)N_NODES * 4, stream);

  k_xw<<<dim3(N_NODES / 64, D / 64), 256, 0, stream>>>(x, W, XW);
  k_deg<<<NE / 256, 256, 0, stream>>>(ei, deg);
  k_scan<<<1, 256, 0, stream>>>(deg, rs, dinv);
  k_fill<<<NE / 256, 256, 0, stream>>>(ei, ei + NE, rs, cur, ecol, eeid);
  k_agg<<<N_NODES, 256, 0, stream>>>(XW, b, deg, rs, ecol, eeid, dinv, out_h, sq);
  k_fused<<<dim3(N_NODES / TM, NSPLIT), 256, 0, stream>>>(out_h, sq, q, temp, cval, cidx);
  k_merge<<<N_NODES / 256, 256, 0, stream>>>(cval, cidx, out_idx, out_rows, out_vals);
}

// Round 14
// 2496.460 us; speedup vs baseline: 1.6943x; 1.0897x over previous
//
#include <hip/hip_runtime.h>
#include <hip/hip_bf16.h>

#define N_NODES 12288
#define D 256
#define NE 196608
#define TOPK 4
#define TM 128
#define TN 128
#define NSPLIT 16
#define CPS (N_NODES / NSPLIT)   // 768 cols per split
#define MAXDEG 256
// MEASURED (rounds 0-9): harness reads d_out as FLOAT32, identity layout:
// [ h 3145728 | top_idx 49152 | rows 49152 | top_vals 49152 ].

// ---------------- insert helpers (top-4, descending) ----------------
__device__ __forceinline__ void ins4(float v, int id, float tv[TOPK], int ti[TOPK]) {
  if (v > tv[3]) {
    tv[3] = v; ti[3] = id;
    if (tv[3] > tv[2]) {
      float a = tv[2]; tv[2] = tv[3]; tv[3] = a; int b = ti[2]; ti[2] = ti[3]; ti[3] = b;
      if (tv[2] > tv[1]) {
        float a2 = tv[1]; tv[1] = tv[2]; tv[2] = a2; int b2 = ti[1]; ti[1] = ti[2]; ti[2] = b2;
        if (tv[1] > tv[0]) {
          float a3 = tv[0]; tv[0] = tv[1]; tv[1] = a3; int b3 = ti[0]; ti[0] = ti[1]; ti[1] = b3;
        }
      }
    }
  }
}

__device__ __forceinline__ void ins4tie(float v, int id, float tv[TOPK], int ti[TOPK]) {
  if ((v > tv[3]) || (v == tv[3] && id < ti[3])) {
    tv[3] = v; ti[3] = id;
    if ((tv[3] > tv[2]) || (tv[3] == tv[2] && ti[3] < ti[2])) {
      float a = tv[2]; tv[2] = tv[3]; tv[3] = a; int b = ti[2]; ti[2] = ti[3]; ti[3] = b;
      if ((tv[2] > tv[1]) || (tv[2] == tv[1] && ti[2] < ti[1])) {
        float a2 = tv[1]; tv[1] = tv[2]; tv[2] = a2; int b2 = ti[1]; ti[1] = ti[2]; ti[2] = b2;
        if ((tv[1] > tv[0]) || (tv[1] == tv[0] && ti[1] < ti[0])) {
          float a3 = tv[0]; tv[0] = tv[1]; tv[1] = a3; int b3 = ti[0]; ti[0] = ti[1]; ti[1] = b3;
        }
      }
    }
  }
}

// ---------------- K1: XW = x @ W ----------------
__global__ __launch_bounds__(256) void k_xw(const float* __restrict__ X,
                                            const float* __restrict__ W,
                                            float* __restrict__ XW) {
  __shared__ float sA[16][65];
  __shared__ float sB[16][65];
  const int tid = threadIdx.x;
  const int ty = tid >> 4, tx = tid & 15;
  const int by = blockIdx.x, bx = blockIdx.y;
  float acc[4][4] = {};
  for (int kk = 0; kk < D; kk += 16) {
    {
      int m = tid >> 2;
      int kq = (tid & 3) << 2;
      const float4 av = *(const float4*)&X[(size_t)(by * 64 + m) * D + kk + kq];
      sA[kq + 0][m] = av.x; sA[kq + 1][m] = av.y; sA[kq + 2][m] = av.z; sA[kq + 3][m] = av.w;
    }
    {
      int r = tid >> 4;
      int c = (tid & 15) << 2;
      const float4 bv = *(const float4*)&W[(size_t)(kk + r) * D + bx * 64 + c];
      sB[r][c + 0] = bv.x; sB[r][c + 1] = bv.y; sB[r][c + 2] = bv.z; sB[r][c + 3] = bv.w;
    }
    __syncthreads();
#pragma unroll
    for (int k = 0; k < 16; ++k) {
      float a[4], b[4];
#pragma unroll
      for (int i = 0; i < 4; i++) a[i] = sA[k][ty + 16 * i];
#pragma unroll
      for (int j = 0; j < 4; j++) b[j] = sB[k][tx + 16 * j];
#pragma unroll
      for (int i = 0; i < 4; i++)
#pragma unroll
        for (int j = 0; j < 4; j++) acc[i][j] = fmaf(a[i], b[j], acc[i][j]);
    }
    __syncthreads();
  }
#pragma unroll
  for (int i = 0; i < 4; i++)
#pragma unroll
    for (int j = 0; j < 4; j++)
      XW[(size_t)(by * 64 + ty + 16 * i) * D + bx * 64 + tx + 16 * j] = acc[i][j];
}

// ---------------- K2: in-degree histogram ----------------
__global__ void k_deg(const int* __restrict__ row, int* __restrict__ deg) {
  int e = blockIdx.x * blockDim.x + threadIdx.x;
  if (e < NE) {
    unsigned r = (unsigned)row[e];
    if (r < N_NODES) atomicAdd(&deg[r], 1);
  }
}

// ---------------- K3: exclusive scan + dinv ----------------
__global__ __launch_bounds__(256) void k_scan(const int* __restrict__ deg,
                                              int* __restrict__ row_start,
                                              float* __restrict__ dinv) {
  __shared__ int part[256];
  const int tid = threadIdx.x;
  const int L = N_NODES / 256;  // 48
  const int base = tid * L;
  int s = 0;
  for (int i = 0; i < L; i++) s += deg[base + i];
  part[tid] = s;
  __syncthreads();
  for (int off = 1; off < 256; off <<= 1) {
    int v = (tid >= off) ? part[tid - off] : 0;
    __syncthreads();
    part[tid] += v;
    __syncthreads();
  }
  int run = part[tid] - s;
  for (int i = 0; i < L; i++) {
    int d = deg[base + i];
    row_start[base + i] = run;
    dinv[base + i] = 1.0f / sqrtf((float)(d + 1));
    run += d;
  }
}

// ---------------- K4: CSR fill ----------------
__global__ void k_fill(const int* __restrict__ row, const int* __restrict__ col,
                       const int* __restrict__ row_start, int* __restrict__ cursor,
                       int* __restrict__ ecol, int* __restrict__ eeid) {
  int e = blockIdx.x * blockDim.x + threadIdx.x;
  if (e >= NE) return;
  unsigned r = (unsigned)row[e];
  if (r >= N_NODES) return;
  int p = atomicAdd(&cursor[r], 1);
  int slot = row_start[r] + p;
  if ((unsigned)slot >= NE) return;
  unsigned c = (unsigned)col[e];
  if (c >= N_NODES) c = 0;
  ecol[slot] = (int)c;
  eeid[slot] = e;
}

// ---------------- K5: aggregation (eid-sorted -> deterministic); h -> d_out ------
__global__ __launch_bounds__(256) void k_agg(const float* __restrict__ XW,
                                             const float* __restrict__ bias,
                                             const int* __restrict__ deg,
                                             const int* __restrict__ row_start,
                                             const int* __restrict__ ecol,
                                             const int* __restrict__ eeid,
                                             const float* __restrict__ dinv,
                                             float* __restrict__ h_out,
                                             float* __restrict__ sq) {
  __shared__ int sc[MAXDEG];
  __shared__ int se[MAXDEG];
  __shared__ float snorm[MAXDEG];
  __shared__ float red[256];
  const int i = blockIdx.x;
  const int tid = threadIdx.x;
  int cnt = deg[i];
  if (cnt > MAXDEG) cnt = MAXDEG;
  if (cnt < 0) cnt = 0;
  const int st = row_start[i];
  for (int t = tid; t < cnt; t += 256) {
    unsigned cc = (unsigned)ecol[st + t];
    sc[t] = (cc < N_NODES) ? (int)cc : 0;
    se[t] = eeid[st + t];
  }
  __syncthreads();
  if (tid == 0) {  // insertion sort by original edge id
    for (int a = 1; a < cnt; ++a) {
      int ce = se[a], cc = sc[a];
      int bp = a - 1;
      while (bp >= 0 && se[bp] > ce) { se[bp + 1] = se[bp]; sc[bp + 1] = sc[bp]; --bp; }
      se[bp + 1] = ce; sc[bp + 1] = cc;
    }
  }
  __syncthreads();
  const float di = dinv[i];
  for (int t = tid; t < cnt; t += 256) snorm[t] = __fmul_rn(di, dinv[sc[t]]);
  __syncthreads();
  float acc = 0.0f;
  for (int t = 0; t < cnt; ++t) {
    float v = XW[(size_t)sc[t] * D + tid];
    acc = __fadd_rn(acc, __fmul_rn(v, snorm[t]));
  }
  acc = __fadd_rn(acc, __fmul_rn(XW[(size_t)i * D + tid], __fmul_rn(di, di)));  // self loop last
  acc = __fadd_rn(acc, bias[tid]);
  h_out[(size_t)i * D + tid] = acc;
  red[tid] = __fmul_rn(acc, acc);
  __syncthreads();
  for (int off = 128; off > 0; off >>= 1) {
    if (tid < off) red[tid] = __fadd_rn(red[tid], red[tid + off]);
    __syncthreads();
  }
  if (tid == 0) sq[i] = red[0];
}

// ---------------- K6 v5: fused d2 + gumbel + top-4 (dbuf pipeline, 2 blocks/CU) --
// Round-13 diagnosis: latency-bound (1 wave/SIMD, VALUBusy 33%, LDS 27%,
// 2 barriers + exposed global staging per k-chunk). v5: LDS double-buffer with
// ONE barrier per chunk; chunk c+2 prefetched global->reg under chunk-c compute;
// launch_bounds(256,2) -> 2 blocks/CU (2 waves/SIMD) for TLP.
// Arithmetic (acc order, lq op order, insert order) IDENTICAL to round 13.
__global__ __launch_bounds__(256, 2) void k_fused(const float* __restrict__ h,
                                                  const float* __restrict__ sq,
                                                  const float* __restrict__ q,
                                                  const float* __restrict__ tempP,
                                                  float* __restrict__ cval,
                                                  int* __restrict__ cidx) {
  __shared__ float4 sA4[2][TM * 9];  // 2 x 18 KB, stride-9-f4 pad
  __shared__ float4 sB4[2][TN * 9];  // 2 x 18 KB   (total 72 KB)
  const int tid = threadIdx.x;
  const int tx = tid & 15;
  const int ty = tid >> 4;
  const int row0 = blockIdx.x * TM;
  const int split = blockIdx.y;
  const int c0 = split * CPS;
  const float T = tempP[0];
  const float4* hf4 = (const float4*)h;

  // staging role: thread covers rows sr+32t (t=0..3) at f4-lane sk
  const int sr = tid >> 3;     // 0..31
  const int sk = tid & 7;      // 0..7

  float sqr[8];
#pragma unroll
  for (int i = 0; i < 8; ++i) sqr[i] = sq[row0 + ty + 16 * i];

  float tv[8][TOPK];
  int ti[8][TOPK];
#pragma unroll
  for (int i = 0; i < 8; ++i)
#pragma unroll
    for (int k = 0; k < TOPK; ++k) { tv[i][k] = -3.0e38f; ti[i][k] = 0; }

  float4 rA[4], rB[4];

  for (int ct = c0; ct < c0 + CPS; ct += TN) {  // 6 col-tiles
    float acc[8][8];
#pragma unroll
    for (int i = 0; i < 8; ++i)
#pragma unroll
      for (int j = 0; j < 8; ++j) acc[i][j] = 0.0f;

    // ---- prologue: chunk0 -> LDS buf0; chunk1 -> regs ----
#pragma unroll
    for (int t = 0; t < 4; ++t) {
      rA[t] = hf4[(size_t)(row0 + sr + 32 * t) * 64 + 0 + sk];
      rB[t] = hf4[(size_t)(ct + sr + 32 * t) * 64 + 0 + sk];
    }
#pragma unroll
    for (int t = 0; t < 4; ++t) {
      sA4[0][(sr + 32 * t) * 9 + sk] = rA[t];
      sB4[0][(sr + 32 * t) * 9 + sk] = rB[t];
    }
#pragma unroll
    for (int t = 0; t < 4; ++t) {
      rA[t] = hf4[(size_t)(row0 + sr + 32 * t) * 64 + 8 + sk];
      rB[t] = hf4[(size_t)(ct + sr + 32 * t) * 64 + 8 + sk];
    }
    __syncthreads();

    for (int c = 0; c < 8; ++c) {   // 8 k-chunks of 32 dims
      const int cur = c & 1;
      if (c + 1 < 8) {              // ds_write chunk c+1 (regs) -> alt buffer
        const int nxt = (c + 1) & 1;
#pragma unroll
        for (int t = 0; t < 4; ++t) {
          sA4[nxt][(sr + 32 * t) * 9 + sk] = rA[t];
          sB4[nxt][(sr + 32 * t) * 9 + sk] = rB[t];
        }
      }
      if (c + 2 < 8) {              // prefetch chunk c+2 -> regs (hidden by FMAs)
        const int kc = (c + 2) * 8;
#pragma unroll
        for (int t = 0; t < 4; ++t) {
          rA[t] = hf4[(size_t)(row0 + sr + 32 * t) * 64 + kc + sk];
          rB[t] = hf4[(size_t)(ct + sr + 32 * t) * 64 + kc + sk];
        }
      }
      // compute chunk c from buf[cur]
#pragma unroll
      for (int kf = 0; kf < 8; ++kf) {
        float4 a[8];
#pragma unroll
        for (int i = 0; i < 8; ++i) a[i] = sA4[cur][(ty + 16 * i) * 9 + kf];
#pragma unroll
        for (int j = 0; j < 8; ++j) {
          const float4 b = sB4[cur][(tx + 16 * j) * 9 + kf];
#pragma unroll
          for (int i = 0; i < 8; ++i) {
            float s = acc[i][j];
            s = fmaf(a[i].x, b.x, s);
            s = fmaf(a[i].y, b.y, s);
            s = fmaf(a[i].z, b.z, s);
            s = fmaf(a[i].w, b.w, s);
            acc[i][j] = s;
          }
        }
      }
      __syncthreads();              // single barrier per chunk
    }

    // epilogue: lq + top-4 insert (ascending c within each thread)
    float sqc[8];
#pragma unroll
    for (int j = 0; j < 8; ++j) sqc[j] = sq[ct + tx + 16 * j];
#pragma unroll
    for (int i = 0; i < 8; ++i) {
      const float* qr = q + (size_t)(row0 + ty + 16 * i) * N_NODES;
#pragma unroll
      for (int j = 0; j < 8; ++j) {
        const int c = ct + tx + 16 * j;
        float s2 = __fadd_rn(sqr[i], sqc[j]);
        float d2 = fmaxf(__fsub_rn(s2, __fmul_rn(2.0f, acc[i][j])), 0.0f);
        float lp = -__fmul_rn(T, d2);
        float gg = logf(-logf(__fadd_rn(qr[c], 1e-8f)));
        ins4(__fsub_rn(lp, gg), c, tv[i], ti[i]);
      }
    }
  }

  // butterfly merge across the 16 col-lanes (same ty), width-16
#pragma unroll
  for (int i = 0; i < 8; ++i) {
#pragma unroll
    for (int m = 1; m < 16; m <<= 1) {
      float ov[TOPK]; int oi[TOPK];
#pragma unroll
      for (int k = 0; k < TOPK; ++k) {
        ov[k] = __shfl_xor(tv[i][k], m, 16);
        oi[k] = __shfl_xor(ti[i][k], m, 16);
      }
#pragma unroll
      for (int k = 0; k < TOPK; ++k) ins4tie(ov[k], oi[k], tv[i], ti[i]);
    }
  }
  if (tx == 0) {
#pragma unroll
    for (int i = 0; i < 8; ++i) {
      int r = row0 + ty + 16 * i;
#pragma unroll
      for (int k = 0; k < TOPK; ++k) {
        cval[((size_t)r * NSPLIT + split) * TOPK + k] = tv[i][k];
        cidx[((size_t)r * NSPLIT + split) * TOPK + k] = ti[i][k];
      }
    }
  }
}

// ---------------- K7: merge splits, write edges + top_vals as FLOAT32 ----------
__global__ __launch_bounds__(256) void k_merge(const float* __restrict__ cval,
                                               const int* __restrict__ cidx,
                                               float* __restrict__ out_idx,
                                               float* __restrict__ out_rows,
                                               float* __restrict__ out_vals) {
  int r = blockIdx.x * blockDim.x + threadIdx.x;
  if (r >= N_NODES) return;
  float bv[TOPK];
  int bi[TOPK];
#pragma unroll
  for (int k = 0; k < TOPK; k++) { bv[k] = -3.0e38f; bi[k] = 0; }
  for (int t = 0; t < NSPLIT * TOPK; t++)
    ins4tie(cval[(size_t)r * NSPLIT * TOPK + t], cidx[(size_t)r * NSPLIT * TOPK + t], bv, bi);
#pragma unroll
  for (int k = 0; k < TOPK; k++) {
    out_idx[r * TOPK + k] = (float)bi[k];
    out_rows[r * TOPK + k] = (float)r;
    out_vals[r * TOPK + k] = bv[k];
  }
}

// ---------------- launcher ----------------
extern "C" void kernel_launch(void* const* d_in, const int* in_sizes, int n_in,
                              void* d_out, int out_size, void* d_ws, size_t ws_size,
                              hipStream_t stream) {
  const float* x = nullptr;     // 3145728
  const float* W = nullptr;     // 65536
  const float* b = nullptr;     // 256
  const float* temp = nullptr;  // 1
  const float* q = nullptr;     // 150994944
  const int* ei = nullptr;      // 393216
  for (int i = 0; i < n_in; ++i) {
    switch (in_sizes[i]) {
      case 3145728:   x = (const float*)d_in[i]; break;
      case 65536:     W = (const float*)d_in[i]; break;
      case 256:       b = (const float*)d_in[i]; break;
      case 1:         temp = (const float*)d_in[i]; break;
      case 150994944: q = (const float*)d_in[i]; break;
      case 393216:    ei = (const int*)d_in[i]; break;
      default: break;
    }
  }
  if (!x || !W || !b || !temp || !q || !ei) return;

  float* out = (float*)d_out;
  float* out_h = out;                                  // [0, 3145728)
  float* out_idx = out + (size_t)N_NODES * D;          // [3145728, 3194880)
  float* out_rows = out_idx + (size_t)N_NODES * TOPK;  // [3194880, 3244032)
  float* out_vals = out_rows + (size_t)N_NODES * TOPK; // [3244032, 3293184)

  char* ws = (char*)d_ws;
  size_t off = 0;
  auto alloc = [&](size_t bytes) {
    char* p = ws + off;
    off += (bytes + 255) & ~(size_t)255;
    return p;
  };
  float* XW = (float*)alloc((size_t)N_NODES * D * 4);
  int* deg = (int*)alloc((size_t)N_NODES * 4);
  int* rs = (int*)alloc((size_t)N_NODES * 4);
  int* cur = (int*)alloc((size_t)N_NODES * 4);
  float* dinv = (float*)alloc((size_t)N_NODES * 4);
  float* sq = (float*)alloc((size_t)N_NODES * 4);
  int* ecol = (int*)alloc((size_t)NE * 4);
  int* eeid = (int*)alloc((size_t)NE * 4);
  float* cval = (float*)alloc((size_t)N_NODES * NSPLIT * TOPK * 4);
  int* cidx = (int*)alloc((size_t)N_NODES * NSPLIT * TOPK * 4);
  if (off > ws_size) return;

  hipMemsetAsync(deg, 0, (size_t)N_NODES * 4, stream);
  hipMemsetAsync(cur, 0, (size_t)N_NODES * 4, stream);

  k_xw<<<dim3(N_NODES / 64, D / 64), 256, 0, stream>>>(x, W, XW);
  k_deg<<<NE / 256, 256, 0, stream>>>(ei, deg);
  k_scan<<<1, 256, 0, stream>>>(deg, rs, dinv);
  k_fill<<<NE / 256, 256, 0, stream>>>(ei, ei + NE, rs, cur, ecol, eeid);
  k_agg<<<N_NODES, 256, 0, stream>>>(XW, b, deg, rs, ecol, eeid, dinv, out_h, sq);
  k_fused<<<dim3(N_NODES / TM, NSPLIT), 256, 0, stream>>>(out_h, sq, q, temp, cval, cidx);
  k_merge<<<N_NODES / 256, 256, 0, stream>>>(cval, cidx, out_idx, out_rows, out_vals);
}

// Round 16
// 2367.408 us; speedup vs baseline: 1.7867x; 1.0545x over previous
//
#include <hip/hip_runtime.h>
#include <hip/hip_bf16.h>

#define N_NODES 12288
#define D 256
#define NE 196608
#define TOPK 4
#define NBLK 96          // 12288 / 128 col-blocks
#define MAXDEG 256
// MEASURED (rounds 0-9): harness reads d_out as FLOAT32, identity layout:
// [ h 3145728 | top_idx 49152 | rows 49152 | top_vals 49152 ].

typedef __attribute__((ext_vector_type(8))) short bf8;     // 8 bf16 (4 VGPR)
typedef __attribute__((ext_vector_type(4))) float f32x4;   // MFMA 16x16 acc

// ---------------- insert helpers ----------------
__device__ __forceinline__ void ins4(float v, int id, float tv[TOPK], int ti[TOPK]) {
  if (v > tv[3]) {
    tv[3] = v; ti[3] = id;
    if (tv[3] > tv[2]) {
      float a = tv[2]; tv[2] = tv[3]; tv[3] = a; int b = ti[2]; ti[2] = ti[3]; ti[3] = b;
      if (tv[2] > tv[1]) {
        float a2 = tv[1]; tv[1] = tv[2]; tv[2] = a2; int b2 = ti[1]; ti[1] = ti[2]; ti[2] = b2;
        if (tv[1] > tv[0]) {
          float a3 = tv[0]; tv[0] = tv[1]; tv[1] = a3; int b3 = ti[0]; ti[0] = ti[1]; ti[1] = b3;
        }
      }
    }
  }
}

__device__ __forceinline__ void ins4tie(float v, int id, float tv[TOPK], int ti[TOPK]) {
  if ((v > tv[3]) || (v == tv[3] && id < ti[3])) {
    tv[3] = v; ti[3] = id;
    if ((tv[3] > tv[2]) || (tv[3] == tv[2] && ti[3] < ti[2])) {
      float a = tv[2]; tv[2] = tv[3]; tv[3] = a; int b = ti[2]; ti[2] = ti[3]; ti[3] = b;
      if ((tv[2] > tv[1]) || (tv[2] == tv[1] && ti[2] < ti[1])) {
        float a2 = tv[1]; tv[1] = tv[2]; tv[2] = a2; int b2 = ti[1]; ti[1] = ti[2]; ti[2] = b2;
        if ((tv[1] > tv[0]) || (tv[1] == tv[0] && ti[1] < ti[0])) {
          float a3 = tv[0]; tv[0] = tv[1]; tv[1] = a3; int b3 = ti[0]; ti[0] = ti[1]; ti[1] = b3;
        }
      }
    }
  }
}

__device__ __forceinline__ void ins8tie(float v, int id, float tv[8], int ti8[8]) {
  if (!((v > tv[7]) || (v == tv[7] && id < ti8[7]))) return;
  tv[7] = v; ti8[7] = id;
#pragma unroll
  for (int k = 7; k > 0; --k) {
    bool sw = (tv[k] > tv[k - 1]) || (tv[k] == tv[k - 1] && ti8[k] < ti8[k - 1]);
    if (sw) {
      float a = tv[k - 1]; tv[k - 1] = tv[k]; tv[k] = a;
      int b = ti8[k - 1]; ti8[k - 1] = ti8[k]; ti8[k] = b;
    }
  }
}

// ---------------- K1: XW = x @ W ----------------
__global__ __launch_bounds__(256) void k_xw(const float* __restrict__ X,
                                            const float* __restrict__ W,
                                            float* __restrict__ XW) {
  __shared__ float sA[16][65];
  __shared__ float sB[16][65];
  const int tid = threadIdx.x;
  const int ty = tid >> 4, tx = tid & 15;
  const int by = blockIdx.x, bx = blockIdx.y;
  float acc[4][4] = {};
  for (int kk = 0; kk < D; kk += 16) {
    {
      int m = tid >> 2;
      int kq = (tid & 3) << 2;
      const float4 av = *(const float4*)&X[(size_t)(by * 64 + m) * D + kk + kq];
      sA[kq + 0][m] = av.x; sA[kq + 1][m] = av.y; sA[kq + 2][m] = av.z; sA[kq + 3][m] = av.w;
    }
    {
      int r = tid >> 4;
      int c = (tid & 15) << 2;
      const float4 bv = *(const float4*)&W[(size_t)(kk + r) * D + bx * 64 + c];
      sB[r][c + 0] = bv.x; sB[r][c + 1] = bv.y; sB[r][c + 2] = bv.z; sB[r][c + 3] = bv.w;
    }
    __syncthreads();
#pragma unroll
    for (int k = 0; k < 16; ++k) {
      float a[4], b[4];
#pragma unroll
      for (int i = 0; i < 4; i++) a[i] = sA[k][ty + 16 * i];
#pragma unroll
      for (int j = 0; j < 4; j++) b[j] = sB[k][tx + 16 * j];
#pragma unroll
      for (int i = 0; i < 4; i++)
#pragma unroll
        for (int j = 0; j < 4; j++) acc[i][j] = fmaf(a[i], b[j], acc[i][j]);
    }
    __syncthreads();
  }
#pragma unroll
  for (int i = 0; i < 4; i++)
#pragma unroll
    for (int j = 0; j < 4; j++)
      XW[(size_t)(by * 64 + ty + 16 * i) * D + bx * 64 + tx + 16 * j] = acc[i][j];
}

// ---------------- K2: in-degree histogram ----------------
__global__ void k_deg(const int* __restrict__ row, int* __restrict__ deg) {
  int e = blockIdx.x * blockDim.x + threadIdx.x;
  if (e < NE) {
    unsigned r = (unsigned)row[e];
    if (r < N_NODES) atomicAdd(&deg[r], 1);
  }
}

// ---------------- K3: exclusive scan + dinv ----------------
__global__ __launch_bounds__(256) void k_scan(const int* __restrict__ deg,
                                              int* __restrict__ row_start,
                                              float* __restrict__ dinv) {
  __shared__ int part[256];
  const int tid = threadIdx.x;
  const int L = N_NODES / 256;  // 48
  const int base = tid * L;
  int s = 0;
  for (int i = 0; i < L; i++) s += deg[base + i];
  part[tid] = s;
  __syncthreads();
  for (int off = 1; off < 256; off <<= 1) {
    int v = (tid >= off) ? part[tid - off] : 0;
    __syncthreads();
    part[tid] += v;
    __syncthreads();
  }
  int run = part[tid] - s;
  for (int i = 0; i < L; i++) {
    int d = deg[base + i];
    row_start[base + i] = run;
    dinv[base + i] = 1.0f / sqrtf((float)(d + 1));
    run += d;
  }
}

// ---------------- K4: CSR fill ----------------
__global__ void k_fill(const int* __restrict__ row, const int* __restrict__ col,
                       const int* __restrict__ row_start, int* __restrict__ cursor,
                       int* __restrict__ ecol, int* __restrict__ eeid) {
  int e = blockIdx.x * blockDim.x + threadIdx.x;
  if (e >= NE) return;
  unsigned r = (unsigned)row[e];
  if (r >= N_NODES) return;
  int p = atomicAdd(&cursor[r], 1);
  int slot = row_start[r] + p;
  if ((unsigned)slot >= NE) return;
  unsigned c = (unsigned)col[e];
  if (c >= N_NODES) c = 0;
  ecol[slot] = (int)c;
  eeid[slot] = e;
}

// ---------------- K5: aggregation (eid-sorted -> deterministic); h -> d_out ------
__global__ __launch_bounds__(256) void k_agg(const float* __restrict__ XW,
                                             const float* __restrict__ bias,
                                             const int* __restrict__ deg,
                                             const int* __restrict__ row_start,
                                             const int* __restrict__ ecol,
                                             const int* __restrict__ eeid,
                                             const float* __restrict__ dinv,
                                             float* __restrict__ h_out,
                                             float* __restrict__ sq) {
  __shared__ int sc[MAXDEG];
  __shared__ int se[MAXDEG];
  __shared__ float snorm[MAXDEG];
  __shared__ float red[256];
  const int i = blockIdx.x;
  const int tid = threadIdx.x;
  int cnt = deg[i];
  if (cnt > MAXDEG) cnt = MAXDEG;
  if (cnt < 0) cnt = 0;
  const int st = row_start[i];
  for (int t = tid; t < cnt; t += 256) {
    unsigned cc = (unsigned)ecol[st + t];
    sc[t] = (cc < N_NODES) ? (int)cc : 0;
    se[t] = eeid[st + t];
  }
  __syncthreads();
  if (tid == 0) {  // insertion sort by original edge id
    for (int a = 1; a < cnt; ++a) {
      int ce = se[a], cc = sc[a];
      int bp = a - 1;
      while (bp >= 0 && se[bp] > ce) { se[bp + 1] = se[bp]; sc[bp + 1] = sc[bp]; --bp; }
      se[bp + 1] = ce; sc[bp + 1] = cc;
    }
  }
  __syncthreads();
  const float di = dinv[i];
  for (int t = tid; t < cnt; t += 256) snorm[t] = __fmul_rn(di, dinv[sc[t]]);
  __syncthreads();
  float acc = 0.0f;
  for (int t = 0; t < cnt; ++t) {
    float v = XW[(size_t)sc[t] * D + tid];
    acc = __fadd_rn(acc, __fmul_rn(v, snorm[t]));
  }
  acc = __fadd_rn(acc, __fmul_rn(XW[(size_t)i * D + tid], __fmul_rn(di, di)));  // self loop last
  acc = __fadd_rn(acc, bias[tid]);
  h_out[(size_t)i * D + tid] = acc;
  red[tid] = __fmul_rn(acc, acc);
  __syncthreads();
  for (int off = 128; off > 0; off >>= 1) {
    if (tid < off) red[tid] = __fadd_rn(red[tid], red[tid + off]);
    __syncthreads();
  }
  if (tid == 0) sq[i] = red[0];
}

// ---------------- K6: h -> (hi, lo) bf16 split ----------------
__global__ __launch_bounds__(256) void k_split(const float* __restrict__ h,
                                               unsigned short* __restrict__ hhi,
                                               unsigned short* __restrict__ hlo) {
  int i = blockIdx.x * 256 + threadIdx.x;  // grid = N*D/256
  float v = h[i];
  __hip_bfloat16 bh = __float2bfloat16(v);
  float hiF = __bfloat162float(bh);
  __hip_bfloat16 bl = __float2bfloat16(v - hiF);
  hhi[i] = *(unsigned short*)&bh;
  hlo[i] = *(unsigned short*)&bl;
}

// ---------------- K7: MFMA split-bf16 GEMM + approx lq + per-block top-4 ---------
// Fix vs round 15: the pair merge now SNAPSHOTS the partner's full top-4 before
// inserting (round-15 interleaved shfl+insert read mutated partner state ->
// duplicated/dropped candidates -> wrong rank-2..4 indices).
__global__ __launch_bounds__(256, 2) void k_gemm(const unsigned short* __restrict__ hhi,
                                                 const unsigned short* __restrict__ hlo,
                                                 const float* __restrict__ sq,
                                                 const float* __restrict__ q,
                                                 const float* __restrict__ tempP,
                                                 float* __restrict__ candv,
                                                 int* __restrict__ candi) {
  __shared__ __align__(16) char smem[128 * 132 * 4];
  unsigned short* stg = (unsigned short*)smem;       // [sel][row][32]
  float (*lqs)[132] = (float(*)[132])smem;
  const int tid = threadIdx.x;
  const int w = tid >> 6, l = tid & 63;
  const int row0 = blockIdx.x * 128, col0 = blockIdx.y * 128;
  const float T = tempP[0];

  f32x4 acc[4][4];
#pragma unroll
  for (int a = 0; a < 4; ++a)
#pragma unroll
    for (int b = 0; b < 4; ++b) acc[a][b] = (f32x4){0.f, 0.f, 0.f, 0.f};

  const int srow = tid >> 1;
  const int sslot0 = (tid & 1) * 2;

  for (int kc = 0; kc < D; kc += 32) {  // 8 K-chunks
    __syncthreads();
    // stage: sel 0=Ahi 1=Alo 2=Bhi 3=Blo; 16B slots XOR-swizzled by (row&3)
#pragma unroll
    for (int sel = 0; sel < 4; ++sel) {
      const unsigned short* src = (sel == 0 || sel == 2) ? hhi : hlo;
      int grow = ((sel < 2) ? row0 : col0) + srow;
#pragma unroll
      for (int p = 0; p < 2; ++p) {
        int slot = sslot0 + p;
        uint4 v = *(const uint4*)&src[(size_t)grow * D + kc + slot * 8];
        *(uint4*)&stg[(sel * 128 + srow) * 32 + ((slot ^ (srow & 3)) * 8)] = v;
      }
    }
    __syncthreads();
    // frags: A row = (w&1)*64 + a*16 + (l&15), k-octet = l>>4
    bf8 Ah[4], Al[4], Bh[4], Bl[4];
    const int koct = l >> 4;
#pragma unroll
    for (int a = 0; a < 4; ++a) {
      int ar = (w & 1) * 64 + a * 16 + (l & 15);
      int as = (koct ^ (ar & 3)) * 8;
      Ah[a] = *(bf8*)&stg[(0 * 128 + ar) * 32 + as];
      Al[a] = *(bf8*)&stg[(1 * 128 + ar) * 32 + as];
      int br = (w >> 1) * 64 + a * 16 + (l & 15);
      int bs = (koct ^ (br & 3)) * 8;
      Bh[a] = *(bf8*)&stg[(2 * 128 + br) * 32 + bs];
      Bl[a] = *(bf8*)&stg[(3 * 128 + br) * 32 + bs];
    }
#pragma unroll
    for (int a = 0; a < 4; ++a)
#pragma unroll
      for (int b = 0; b < 4; ++b) {
        acc[a][b] = __builtin_amdgcn_mfma_f32_16x16x32_bf16(Ah[a], Bh[b], acc[a][b], 0, 0, 0);
        acc[a][b] = __builtin_amdgcn_mfma_f32_16x16x32_bf16(Ah[a], Bl[b], acc[a][b], 0, 0, 0);
        acc[a][b] = __builtin_amdgcn_mfma_f32_16x16x32_bf16(Al[a], Bh[b], acc[a][b], 0, 0, 0);
      }
  }
  __syncthreads();
  // epilogue: approx lq -> LDS (C/D map: col=lane&15, row=(lane>>4)*4+reg)
#pragma unroll
  for (int a = 0; a < 4; ++a)
#pragma unroll
    for (int b = 0; b < 4; ++b)
#pragma unroll
      for (int r = 0; r < 4; ++r) {
        int rowblk = (w & 1) * 64 + a * 16 + (l >> 4) * 4 + r;
        int colblk = (w >> 1) * 64 + b * 16 + (l & 15);
        int grow = row0 + rowblk, gcol = col0 + colblk;
        float dot = acc[a][b][r];
        float d2 = fmaxf((sq[grow] + sq[gcol]) - 2.0f * dot, 0.0f);
        float gg = logf(-logf(q[(size_t)grow * N_NODES + gcol] + 1e-8f));
        lqs[rowblk][colblk] = -T * d2 - gg;
      }
  __syncthreads();
  // per-row approx top-4 over this block's 128 cols
  {
    int rw = tid >> 1, cbase = (tid & 1) * 64;
    float tv[TOPK]; int ti4[TOPK];
#pragma unroll
    for (int k = 0; k < TOPK; ++k) { tv[k] = -3.0e38f; ti4[k] = 0; }
    for (int i = 0; i < 64; ++i) ins4(lqs[rw][cbase + i], col0 + cbase + i, tv, ti4);
    // SNAPSHOT the partner's full list first, then insert (r15 bugfix)
    float ov[TOPK]; int oi[TOPK];
#pragma unroll
    for (int k = 0; k < TOPK; ++k) {
      ov[k] = __shfl_xor(tv[k], 1);
      oi[k] = __shfl_xor(ti4[k], 1);
    }
#pragma unroll
    for (int k = 0; k < TOPK; ++k) ins4tie(ov[k], oi[k], tv, ti4);
    if ((tid & 1) == 0) {
      size_t base = ((size_t)(row0 + rw) * NBLK + blockIdx.y) * TOPK;
#pragma unroll
      for (int k = 0; k < TOPK; ++k) { candv[base + k] = tv[k]; candi[base + k] = ti4[k]; }
    }
  }
}

// ---------------- K8: per-row merge 384 cands -> approx top-8 -> EXACT rerank ----
__global__ __launch_bounds__(256) void k_rerank(const float* __restrict__ candv,
                                                const int* __restrict__ candi,
                                                const float* __restrict__ h,
                                                const float* __restrict__ sq,
                                                const float* __restrict__ q,
                                                const float* __restrict__ tempP,
                                                float* __restrict__ out_idx,
                                                float* __restrict__ out_rows,
                                                float* __restrict__ out_vals) {
  const int tid = threadIdx.x;
  const int row = blockIdx.x * 4 + (tid >> 6);  // one wave per row
  const int l = tid & 63;
  const float T = tempP[0];
  float tv[8]; int ti8[8];
#pragma unroll
  for (int k = 0; k < 8; ++k) { tv[k] = -3.0e38f; ti8[k] = 0; }
  size_t cb = (size_t)row * (NBLK * TOPK);
  for (int i = 0; i < 6; ++i)
    ins8tie(candv[cb + i * 64 + l], candi[cb + i * 64 + l], tv, ti8);
  // self-sentinel: guarantee c=row is reranked (lane 0 only -> one copy)
  if (l == 0) ins8tie(3.0e38f, row, tv, ti8);
#pragma unroll
  for (int m = 1; m < 64; m <<= 1) {  // snapshot butterfly -> global approx top-8
    float ov[8]; int oi[8];
#pragma unroll
    for (int k = 0; k < 8; ++k) { ov[k] = __shfl_xor(tv[k], m); oi[k] = __shfl_xor(ti8[k], m); }
#pragma unroll
    for (int k = 0; k < 8; ++k) ins8tie(ov[k], oi[k], tv, ti8);
  }
  // exact fp32 rerank of the 8 candidates
  float4 hr = *(const float4*)&h[(size_t)row * D + l * 4];
  float lqe[8];
#pragma unroll
  for (int k = 0; k < 8; ++k) {
    int c = ti8[k];
    float4 hc = *(const float4*)&h[(size_t)c * D + l * 4];
    float p = fmaf(hr.x, hc.x, 0.0f);
    p = fmaf(hr.y, hc.y, p);
    p = fmaf(hr.z, hc.z, p);
    p = fmaf(hr.w, hc.w, p);
#pragma unroll
    for (int m = 1; m < 64; m <<= 1) p += __shfl_xor(p, m);
    float d2 = fmaxf(__fsub_rn(__fadd_rn(sq[row], sq[c]), __fmul_rn(2.0f, p)), 0.0f);
    float lp = -__fmul_rn(T, d2);
    float gg = logf(-logf(__fadd_rn(q[(size_t)row * N_NODES + c], 1e-8f)));
    lqe[k] = __fsub_rn(lp, gg);
  }
  float bv[TOPK]; int bi[TOPK];
#pragma unroll
  for (int k = 0; k < TOPK; ++k) { bv[k] = -3.0e38f; bi[k] = 0; }
#pragma unroll
  for (int k = 0; k < 8; ++k) {   // dedupe guard (sentinel + organic self)
    bool dup = false;
#pragma unroll
    for (int k2 = 0; k2 < 8; ++k2)
      if (k2 < k) dup = dup || (ti8[k2] == ti8[k]);
    if (!dup) ins4tie(lqe[k], ti8[k], bv, bi);
  }
  if (l == 0) {
#pragma unroll
    for (int k = 0; k < TOPK; ++k) {
      out_idx[(size_t)row * TOPK + k] = (float)bi[k];
      out_rows[(size_t)row * TOPK + k] = (float)row;
      out_vals[(size_t)row * TOPK + k] = bv[k];
    }
  }
}

// ---------------- launcher ----------------
extern "C" void kernel_launch(void* const* d_in, const int* in_sizes, int n_in,
                              void* d_out, int out_size, void* d_ws, size_t ws_size,
                              hipStream_t stream) {
  const float* x = nullptr;     // 3145728
  const float* W = nullptr;     // 65536
  const float* b = nullptr;     // 256
  const float* temp = nullptr;  // 1
  const float* q = nullptr;     // 150994944
  const int* ei = nullptr;      // 393216
  for (int i = 0; i < n_in; ++i) {
    switch (in_sizes[i]) {
      case 3145728:   x = (const float*)d_in[i]; break;
      case 65536:     W = (const float*)d_in[i]; break;
      case 256:       b = (const float*)d_in[i]; break;
      case 1:         temp = (const float*)d_in[i]; break;
      case 150994944: q = (const float*)d_in[i]; break;
      case 393216:    ei = (const int*)d_in[i]; break;
      default: break;
    }
  }
  if (!x || !W || !b || !temp || !q || !ei) return;

  float* out = (float*)d_out;
  float* out_h = out;                                  // [0, 3145728)
  float* out_idx = out + (size_t)N_NODES * D;          // [3145728, 3194880)
  float* out_rows = out_idx + (size_t)N_NODES * TOPK;  // [3194880, 3244032)
  float* out_vals = out_rows + (size_t)N_NODES * TOPK; // [3244032, 3293184)

  char* ws = (char*)d_ws;
  size_t off = 0;
  auto alloc = [&](size_t bytes) {
    char* p = ws + off;
    off += (bytes + 255) & ~(size_t)255;
    return p;
  };
  float* XW = (float*)alloc((size_t)N_NODES * D * 4);  // reused as hhi/hlo after k_agg
  int* deg = (int*)alloc((size_t)N_NODES * 4);
  int* rs = (int*)alloc((size_t)N_NODES * 4);
  int* cur = (int*)alloc((size_t)N_NODES * 4);
  float* dinv = (float*)alloc((size_t)N_NODES * 4);
  float* sq = (float*)alloc((size_t)N_NODES * 4);
  int* ecol = (int*)alloc((size_t)NE * 4);
  int* eeid = (int*)alloc((size_t)NE * 4);
  float* candv = (float*)alloc((size_t)N_NODES * NBLK * TOPK * 4);  // 18.9 MB
  int* candi = (int*)alloc((size_t)N_NODES * NBLK * TOPK * 4);      // 18.9 MB
  if (off > ws_size) return;  // loud zero-output beacon if ws too small

  hipMemsetAsync(deg, 0, (size_t)N_NODES * 4, stream);
  hipMemsetAsync(cur, 0, (size_t)N_NODES * 4, stream);

  k_xw<<<dim3(N_NODES / 64, D / 64), 256, 0, stream>>>(x, W, XW);
  k_deg<<<NE / 256, 256, 0, stream>>>(ei, deg);
  k_scan<<<1, 256, 0, stream>>>(deg, rs, dinv);
  k_fill<<<NE / 256, 256, 0, stream>>>(ei, ei + NE, rs, cur, ecol, eeid);
  k_agg<<<N_NODES, 256, 0, stream>>>(XW, b, deg, rs, ecol, eeid, dinv, out_h, sq);

  // XW dead -> reuse as bf16 hi/lo arrays (exact fit: N*D*2B*2 = N*D*4B)
  unsigned short* hhi = (unsigned short*)XW;
  unsigned short* hlo = hhi + (size_t)N_NODES * D;
  k_split<<<(N_NODES * D) / 256, 256, 0, stream>>>(out_h, hhi, hlo);
  k_gemm<<<dim3(NBLK, NBLK), 256, 0, stream>>>(hhi, hlo, sq, q, temp, candv, candi);
  k_rerank<<<N_NODES / 4, 256, 0, stream>>>(candv, candi, out_h, sq, q, temp,
                                            out_idx, out_rows, out_vals);
}

// Round 17
// 1297.314 us; speedup vs baseline: 3.2604x; 1.8249x over previous
//
#include <hip/hip_runtime.h>
#include <hip/hip_bf16.h>

#define N_NODES 12288
#define D 256
#define NE 196608
#define TOPK 4
#define NBLK 96          // 12288 / 128 col-blocks
#define MAXDEG 256
// MEASURED (rounds 0-9): harness reads d_out as FLOAT32, identity layout:
// [ h 3145728 | top_idx 49152 | rows 49152 | top_vals 49152 ].

typedef __attribute__((ext_vector_type(8))) short bf8;     // 8 bf16 (4 VGPR)
typedef __attribute__((ext_vector_type(4))) float f32x4;   // MFMA 16x16 acc

// ---------------- insert helpers ----------------
__device__ __forceinline__ void ins4(float v, int id, float tv[TOPK], int ti[TOPK]) {
  if (v > tv[3]) {
    tv[3] = v; ti[3] = id;
    if (tv[3] > tv[2]) {
      float a = tv[2]; tv[2] = tv[3]; tv[3] = a; int b = ti[2]; ti[2] = ti[3]; ti[3] = b;
      if (tv[2] > tv[1]) {
        float a2 = tv[1]; tv[1] = tv[2]; tv[2] = a2; int b2 = ti[1]; ti[1] = ti[2]; ti[2] = b2;
        if (tv[1] > tv[0]) {
          float a3 = tv[0]; tv[0] = tv[1]; tv[1] = a3; int b3 = ti[0]; ti[0] = ti[1]; ti[1] = b3;
        }
      }
    }
  }
}

__device__ __forceinline__ void ins4tie(float v, int id, float tv[TOPK], int ti[TOPK]) {
  if ((v > tv[3]) || (v == tv[3] && id < ti[3])) {
    tv[3] = v; ti[3] = id;
    if ((tv[3] > tv[2]) || (tv[3] == tv[2] && ti[3] < ti[2])) {
      float a = tv[2]; tv[2] = tv[3]; tv[3] = a; int b = ti[2]; ti[2] = ti[3]; ti[3] = b;
      if ((tv[2] > tv[1]) || (tv[2] == tv[1] && ti[2] < ti[1])) {
        float a2 = tv[1]; tv[1] = tv[2]; tv[2] = a2; int b2 = ti[1]; ti[1] = ti[2]; ti[2] = b2;
        if ((tv[1] > tv[0]) || (tv[1] == tv[0] && ti[1] < ti[0])) {
          float a3 = tv[0]; tv[0] = tv[1]; tv[1] = a3; int b3 = ti[0]; ti[0] = ti[1]; ti[1] = b3;
        }
      }
    }
  }
}

__device__ __forceinline__ void ins8tie(float v, int id, float tv[8], int ti8[8]) {
  if (!((v > tv[7]) || (v == tv[7] && id < ti8[7]))) return;
  tv[7] = v; ti8[7] = id;
#pragma unroll
  for (int k = 7; k > 0; --k) {
    bool sw = (tv[k] > tv[k - 1]) || (tv[k] == tv[k - 1] && ti8[k] < ti8[k - 1]);
    if (sw) {
      float a = tv[k - 1]; tv[k - 1] = tv[k]; tv[k] = a;
      int b = ti8[k - 1]; ti8[k - 1] = ti8[k]; ti8[k] = b;
    }
  }
}

// ---------------- K1: XW = x @ W ----------------
__global__ __launch_bounds__(256) void k_xw(const float* __restrict__ X,
                                            const float* __restrict__ W,
                                            float* __restrict__ XW) {
  __shared__ float sA[16][65];
  __shared__ float sB[16][65];
  const int tid = threadIdx.x;
  const int ty = tid >> 4, tx = tid & 15;
  const int by = blockIdx.x, bx = blockIdx.y;
  float acc[4][4] = {};
  for (int kk = 0; kk < D; kk += 16) {
    {
      int m = tid >> 2;
      int kq = (tid & 3) << 2;
      const float4 av = *(const float4*)&X[(size_t)(by * 64 + m) * D + kk + kq];
      sA[kq + 0][m] = av.x; sA[kq + 1][m] = av.y; sA[kq + 2][m] = av.z; sA[kq + 3][m] = av.w;
    }
    {
      int r = tid >> 4;
      int c = (tid & 15) << 2;
      const float4 bv = *(const float4*)&W[(size_t)(kk + r) * D + bx * 64 + c];
      sB[r][c + 0] = bv.x; sB[r][c + 1] = bv.y; sB[r][c + 2] = bv.z; sB[r][c + 3] = bv.w;
    }
    __syncthreads();
#pragma unroll
    for (int k = 0; k < 16; ++k) {
      float a[4], b[4];
#pragma unroll
      for (int i = 0; i < 4; i++) a[i] = sA[k][ty + 16 * i];
#pragma unroll
      for (int j = 0; j < 4; j++) b[j] = sB[k][tx + 16 * j];
#pragma unroll
      for (int i = 0; i < 4; i++)
#pragma unroll
        for (int j = 0; j < 4; j++) acc[i][j] = fmaf(a[i], b[j], acc[i][j]);
    }
    __syncthreads();
  }
#pragma unroll
  for (int i = 0; i < 4; i++)
#pragma unroll
    for (int j = 0; j < 4; j++)
      XW[(size_t)(by * 64 + ty + 16 * i) * D + bx * 64 + tx + 16 * j] = acc[i][j];
}

// ---------------- K2: in-degree histogram ----------------
__global__ void k_deg(const int* __restrict__ row, int* __restrict__ deg) {
  int e = blockIdx.x * blockDim.x + threadIdx.x;
  if (e < NE) {
    unsigned r = (unsigned)row[e];
    if (r < N_NODES) atomicAdd(&deg[r], 1);
  }
}

// ---------------- K3: exclusive scan + dinv ----------------
__global__ __launch_bounds__(256) void k_scan(const int* __restrict__ deg,
                                              int* __restrict__ row_start,
                                              float* __restrict__ dinv) {
  __shared__ int part[256];
  const int tid = threadIdx.x;
  const int L = N_NODES / 256;  // 48
  const int base = tid * L;
  int s = 0;
  for (int i = 0; i < L; i++) s += deg[base + i];
  part[tid] = s;
  __syncthreads();
  for (int off = 1; off < 256; off <<= 1) {
    int v = (tid >= off) ? part[tid - off] : 0;
    __syncthreads();
    part[tid] += v;
    __syncthreads();
  }
  int run = part[tid] - s;
  for (int i = 0; i < L; i++) {
    int d = deg[base + i];
    row_start[base + i] = run;
    dinv[base + i] = 1.0f / sqrtf((float)(d + 1));
    run += d;
  }
}

// ---------------- K4: CSR fill ----------------
__global__ void k_fill(const int* __restrict__ row, const int* __restrict__ col,
                       const int* __restrict__ row_start, int* __restrict__ cursor,
                       int* __restrict__ ecol, int* __restrict__ eeid) {
  int e = blockIdx.x * blockDim.x + threadIdx.x;
  if (e >= NE) return;
  unsigned r = (unsigned)row[e];
  if (r >= N_NODES) return;
  int p = atomicAdd(&cursor[r], 1);
  int slot = row_start[r] + p;
  if ((unsigned)slot >= NE) return;
  unsigned c = (unsigned)col[e];
  if (c >= N_NODES) c = 0;
  ecol[slot] = (int)c;
  eeid[slot] = e;
}

// ---------------- K5: aggregation (eid-sorted -> deterministic); h -> d_out ------
__global__ __launch_bounds__(256) void k_agg(const float* __restrict__ XW,
                                             const float* __restrict__ bias,
                                             const int* __restrict__ deg,
                                             const int* __restrict__ row_start,
                                             const int* __restrict__ ecol,
                                             const int* __restrict__ eeid,
                                             const float* __restrict__ dinv,
                                             float* __restrict__ h_out,
                                             float* __restrict__ sq) {
  __shared__ int sc[MAXDEG];
  __shared__ int se[MAXDEG];
  __shared__ float snorm[MAXDEG];
  __shared__ float red[256];
  const int i = blockIdx.x;
  const int tid = threadIdx.x;
  int cnt = deg[i];
  if (cnt > MAXDEG) cnt = MAXDEG;
  if (cnt < 0) cnt = 0;
  const int st = row_start[i];
  for (int t = tid; t < cnt; t += 256) {
    unsigned cc = (unsigned)ecol[st + t];
    sc[t] = (cc < N_NODES) ? (int)cc : 0;
    se[t] = eeid[st + t];
  }
  __syncthreads();
  if (tid == 0) {  // insertion sort by original edge id
    for (int a = 1; a < cnt; ++a) {
      int ce = se[a], cc = sc[a];
      int bp = a - 1;
      while (bp >= 0 && se[bp] > ce) { se[bp + 1] = se[bp]; sc[bp + 1] = sc[bp]; --bp; }
      se[bp + 1] = ce; sc[bp + 1] = cc;
    }
  }
  __syncthreads();
  const float di = dinv[i];
  for (int t = tid; t < cnt; t += 256) snorm[t] = __fmul_rn(di, dinv[sc[t]]);
  __syncthreads();
  float acc = 0.0f;
  for (int t = 0; t < cnt; ++t) {
    float v = XW[(size_t)sc[t] * D + tid];
    acc = __fadd_rn(acc, __fmul_rn(v, snorm[t]));
  }
  acc = __fadd_rn(acc, __fmul_rn(XW[(size_t)i * D + tid], __fmul_rn(di, di)));  // self loop last
  acc = __fadd_rn(acc, bias[tid]);
  h_out[(size_t)i * D + tid] = acc;
  red[tid] = __fmul_rn(acc, acc);
  __syncthreads();
  for (int off = 128; off > 0; off >>= 1) {
    if (tid < off) red[tid] = __fadd_rn(red[tid], red[tid + off]);
    __syncthreads();
  }
  if (tid == 0) sq[i] = red[0];
}

// ---------------- K6: h -> (hi, lo) bf16 split ----------------
__global__ __launch_bounds__(256) void k_split(const float* __restrict__ h,
                                               unsigned short* __restrict__ hhi,
                                               unsigned short* __restrict__ hlo) {
  int i = blockIdx.x * 256 + threadIdx.x;  // grid = N*D/256
  float v = h[i];
  __hip_bfloat16 bh = __float2bfloat16(v);
  float hiF = __bfloat162float(bh);
  __hip_bfloat16 bl = __float2bfloat16(v - hiF);
  hhi[i] = *(unsigned short*)&bh;
  hlo[i] = *(unsigned short*)&bl;
}

// ---------------- K7: MFMA split-bf16 GEMM + approx lq + per-block top-4 ---------
__global__ __launch_bounds__(256, 2) void k_gemm(const unsigned short* __restrict__ hhi,
                                                 const unsigned short* __restrict__ hlo,
                                                 const float* __restrict__ sq,
                                                 const float* __restrict__ q,
                                                 const float* __restrict__ tempP,
                                                 float* __restrict__ candv,
                                                 int* __restrict__ candi) {
  __shared__ __align__(16) char smem[128 * 132 * 4];
  unsigned short* stg = (unsigned short*)smem;       // [sel][row][32]
  float (*lqs)[132] = (float(*)[132])smem;
  const int tid = threadIdx.x;
  const int w = tid >> 6, l = tid & 63;
  const int row0 = blockIdx.x * 128, col0 = blockIdx.y * 128;
  const float T = tempP[0];

  f32x4 acc[4][4];
#pragma unroll
  for (int a = 0; a < 4; ++a)
#pragma unroll
    for (int b = 0; b < 4; ++b) acc[a][b] = (f32x4){0.f, 0.f, 0.f, 0.f};

  const int srow = tid >> 1;
  const int sslot0 = (tid & 1) * 2;

  for (int kc = 0; kc < D; kc += 32) {  // 8 K-chunks
    __syncthreads();
    // stage: sel 0=Ahi 1=Alo 2=Bhi 3=Blo; 16B slots XOR-swizzled by (row&3)
#pragma unroll
    for (int sel = 0; sel < 4; ++sel) {
      const unsigned short* src = (sel == 0 || sel == 2) ? hhi : hlo;
      int grow = ((sel < 2) ? row0 : col0) + srow;
#pragma unroll
      for (int p = 0; p < 2; ++p) {
        int slot = sslot0 + p;
        uint4 v = *(const uint4*)&src[(size_t)grow * D + kc + slot * 8];
        *(uint4*)&stg[(sel * 128 + srow) * 32 + ((slot ^ (srow & 3)) * 8)] = v;
      }
    }
    __syncthreads();
    // frags: A row = (w&1)*64 + a*16 + (l&15), k-octet = l>>4
    bf8 Ah[4], Al[4], Bh[4], Bl[4];
    const int koct = l >> 4;
#pragma unroll
    for (int a = 0; a < 4; ++a) {
      int ar = (w & 1) * 64 + a * 16 + (l & 15);
      int as = (koct ^ (ar & 3)) * 8;
      Ah[a] = *(bf8*)&stg[(0 * 128 + ar) * 32 + as];
      Al[a] = *(bf8*)&stg[(1 * 128 + ar) * 32 + as];
      int br = (w >> 1) * 64 + a * 16 + (l & 15);
      int bs = (koct ^ (br & 3)) * 8;
      Bh[a] = *(bf8*)&stg[(2 * 128 + br) * 32 + bs];
      Bl[a] = *(bf8*)&stg[(3 * 128 + br) * 32 + bs];
    }
#pragma unroll
    for (int a = 0; a < 4; ++a)
#pragma unroll
      for (int b = 0; b < 4; ++b) {
        acc[a][b] = __builtin_amdgcn_mfma_f32_16x16x32_bf16(Ah[a], Bh[b], acc[a][b], 0, 0, 0);
        acc[a][b] = __builtin_amdgcn_mfma_f32_16x16x32_bf16(Ah[a], Bl[b], acc[a][b], 0, 0, 0);
        acc[a][b] = __builtin_amdgcn_mfma_f32_16x16x32_bf16(Al[a], Bh[b], acc[a][b], 0, 0, 0);
      }
  }
  __syncthreads();
  // epilogue: approx lq -> LDS (C/D map: col=lane&15, row=(lane>>4)*4+reg)
#pragma unroll
  for (int a = 0; a < 4; ++a)
#pragma unroll
    for (int b = 0; b < 4; ++b)
#pragma unroll
      for (int r = 0; r < 4; ++r) {
        int rowblk = (w & 1) * 64 + a * 16 + (l >> 4) * 4 + r;
        int colblk = (w >> 1) * 64 + b * 16 + (l & 15);
        int grow = row0 + rowblk, gcol = col0 + colblk;
        float dot = acc[a][b][r];
        float d2 = fmaxf((sq[grow] + sq[gcol]) - 2.0f * dot, 0.0f);
        float gg = logf(-logf(q[(size_t)grow * N_NODES + gcol] + 1e-8f));
        lqs[rowblk][colblk] = -T * d2 - gg;
      }
  __syncthreads();
  // per-row approx top-4 over this block's 128 cols (snapshot pair-merge)
  {
    int rw = tid >> 1, cbase = (tid & 1) * 64;
    float tv[TOPK]; int ti4[TOPK];
#pragma unroll
    for (int k = 0; k < TOPK; ++k) { tv[k] = -3.0e38f; ti4[k] = 0; }
    for (int i = 0; i < 64; ++i) ins4(lqs[rw][cbase + i], col0 + cbase + i, tv, ti4);
    float ov[TOPK]; int oi[TOPK];
#pragma unroll
    for (int k = 0; k < TOPK; ++k) {
      ov[k] = __shfl_xor(tv[k], 1);
      oi[k] = __shfl_xor(ti4[k], 1);
    }
#pragma unroll
    for (int k = 0; k < TOPK; ++k) ins4tie(ov[k], oi[k], tv, ti4);
    if ((tid & 1) == 0) {
      size_t base = ((size_t)(row0 + rw) * NBLK + blockIdx.y) * TOPK;
#pragma unroll
      for (int k = 0; k < TOPK; ++k) { candv[base + k] = tv[k]; candi[base + k] = ti4[k]; }
    }
  }
}

// ---------------- K8a: per-(row, chunk-of-48) serial top-8 (pure TLP) ----------
// r16 diagnosis: one-wave-per-row butterfly merge = long serial shfl+insert
// chain, latency-bound (1180 us, VALUBusy 30%, Occ 11%). Split into thread-
// parallel partial merges: 98k independent threads, no shfl, no barrier.
__global__ __launch_bounds__(256) void k_cmerge1(const float* __restrict__ candv,
                                                 const int* __restrict__ candi,
                                                 float* __restrict__ pv8,
                                                 int* __restrict__ pi8) {
  int gid = blockIdx.x * 256 + threadIdx.x;      // [0, 12288*8)
  int row = gid >> 3, chunk = gid & 7;
  size_t base = (size_t)row * (NBLK * TOPK) + chunk * 48;
  float tv[8]; int ti8[8];
#pragma unroll
  for (int k = 0; k < 8; ++k) { tv[k] = -3.0e38f; ti8[k] = 0; }
  for (int i = 0; i < 48; ++i) ins8tie(candv[base + i], candi[base + i], tv, ti8);
  size_t ob = (size_t)gid * 8;
#pragma unroll
  for (int k = 0; k < 8; ++k) { pv8[ob + k] = tv[k]; pi8[ob + k] = ti8[k]; }
}

// ---------------- K8b: per-row merge of 8 partials + self-sentinel -------------
__global__ __launch_bounds__(256) void k_cmerge2(const float* __restrict__ pv8,
                                                 const int* __restrict__ pi8,
                                                 float* __restrict__ fv8,
                                                 int* __restrict__ fi8) {
  int row = blockIdx.x * 256 + threadIdx.x;      // [0, 12288)
  size_t base = (size_t)row * 64;
  float tv[8]; int ti8[8];
#pragma unroll
  for (int k = 0; k < 8; ++k) { tv[k] = -3.0e38f; ti8[k] = 0; }
  for (int i = 0; i < 64; ++i) ins8tie(pv8[base + i], pi8[base + i], tv, ti8);
  ins8tie(3.0e38f, row, tv, ti8);                // self-sentinel
  size_t ob = (size_t)row * 8;
#pragma unroll
  for (int k = 0; k < 8; ++k) { fv8[ob + k] = tv[k]; fi8[ob + k] = ti8[k]; }
}

// ---------------- K8c: exact fp32 rerank of final 8 (one wave per row) ---------
__global__ __launch_bounds__(256) void k_exact(const int* __restrict__ fi8,
                                               const float* __restrict__ h,
                                               const float* __restrict__ sq,
                                               const float* __restrict__ q,
                                               const float* __restrict__ tempP,
                                               float* __restrict__ out_idx,
                                               float* __restrict__ out_rows,
                                               float* __restrict__ out_vals) {
  const int tid = threadIdx.x;
  const int row = blockIdx.x * 4 + (tid >> 6);
  const int l = tid & 63;
  const float T = tempP[0];
  int ti8[8];
#pragma unroll
  for (int k = 0; k < 8; ++k) ti8[k] = fi8[(size_t)row * 8 + k];
  float4 hr = *(const float4*)&h[(size_t)row * D + l * 4];
  float lqe[8];
#pragma unroll
  for (int k = 0; k < 8; ++k) {
    int c = ti8[k];
    float4 hc = *(const float4*)&h[(size_t)c * D + l * 4];
    float p = fmaf(hr.x, hc.x, 0.0f);
    p = fmaf(hr.y, hc.y, p);
    p = fmaf(hr.z, hc.z, p);
    p = fmaf(hr.w, hc.w, p);
#pragma unroll
    for (int m = 1; m < 64; m <<= 1) p += __shfl_xor(p, m);
    float d2 = fmaxf(__fsub_rn(__fadd_rn(sq[row], sq[c]), __fmul_rn(2.0f, p)), 0.0f);
    float lp = -__fmul_rn(T, d2);
    float gg = logf(-logf(__fadd_rn(q[(size_t)row * N_NODES + c], 1e-8f)));
    lqe[k] = __fsub_rn(lp, gg);
  }
  float bv[TOPK]; int bi[TOPK];
#pragma unroll
  for (int k = 0; k < TOPK; ++k) { bv[k] = -3.0e38f; bi[k] = 0; }
#pragma unroll
  for (int k = 0; k < 8; ++k) {   // dedupe guard (sentinel + organic self)
    bool dup = false;
#pragma unroll
    for (int k2 = 0; k2 < 8; ++k2)
      if (k2 < k) dup = dup || (ti8[k2] == ti8[k]);
    if (!dup) ins4tie(lqe[k], ti8[k], bv, bi);
  }
  if (l == 0) {
#pragma unroll
    for (int k = 0; k < TOPK; ++k) {
      out_idx[(size_t)row * TOPK + k] = (float)bi[k];
      out_rows[(size_t)row * TOPK + k] = (float)row;
      out_vals[(size_t)row * TOPK + k] = bv[k];
    }
  }
}

// ---------------- launcher ----------------
extern "C" void kernel_launch(void* const* d_in, const int* in_sizes, int n_in,
                              void* d_out, int out_size, void* d_ws, size_t ws_size,
                              hipStream_t stream) {
  const float* x = nullptr;     // 3145728
  const float* W = nullptr;     // 65536
  const float* b = nullptr;     // 256
  const float* temp = nullptr;  // 1
  const float* q = nullptr;     // 150994944
  const int* ei = nullptr;      // 393216
  for (int i = 0; i < n_in; ++i) {
    switch (in_sizes[i]) {
      case 3145728:   x = (const float*)d_in[i]; break;
      case 65536:     W = (const float*)d_in[i]; break;
      case 256:       b = (const float*)d_in[i]; break;
      case 1:         temp = (const float*)d_in[i]; break;
      case 150994944: q = (const float*)d_in[i]; break;
      case 393216:    ei = (const int*)d_in[i]; break;
      default: break;
    }
  }
  if (!x || !W || !b || !temp || !q || !ei) return;

  float* out = (float*)d_out;
  float* out_h = out;                                  // [0, 3145728)
  float* out_idx = out + (size_t)N_NODES * D;          // [3145728, 3194880)
  float* out_rows = out_idx + (size_t)N_NODES * TOPK;  // [3194880, 3244032)
  float* out_vals = out_rows + (size_t)N_NODES * TOPK; // [3244032, 3293184)

  char* ws = (char*)d_ws;
  size_t off = 0;
  auto alloc = [&](size_t bytes) {
    char* p = ws + off;
    off += (bytes + 255) & ~(size_t)255;
    return p;
  };
  float* XW = (float*)alloc((size_t)N_NODES * D * 4);  // reused as hhi/hlo after k_agg
  int* deg = (int*)alloc((size_t)N_NODES * 4);
  int* rs = (int*)alloc((size_t)N_NODES * 4);
  int* cur = (int*)alloc((size_t)N_NODES * 4);
  float* dinv = (float*)alloc((size_t)N_NODES * 4);
  float* sq = (float*)alloc((size_t)N_NODES * 4);
  int* ecol = (int*)alloc((size_t)NE * 4);
  int* eeid = (int*)alloc((size_t)NE * 4);
  float* candv = (float*)alloc((size_t)N_NODES * NBLK * TOPK * 4);  // 18.9 MB
  int* candi = (int*)alloc((size_t)N_NODES * NBLK * TOPK * 4);      // 18.9 MB
  float* pv8 = (float*)alloc((size_t)N_NODES * 64 * 4);             // 3.1 MB
  int* pi8 = (int*)alloc((size_t)N_NODES * 64 * 4);                 // 3.1 MB
  float* fv8 = (float*)alloc((size_t)N_NODES * 8 * 4);              // 0.4 MB
  int* fi8 = (int*)alloc((size_t)N_NODES * 8 * 4);                  // 0.4 MB
  if (off > ws_size) return;  // loud zero-output beacon if ws too small

  hipMemsetAsync(deg, 0, (size_t)N_NODES * 4, stream);
  hipMemsetAsync(cur, 0, (size_t)N_NODES * 4, stream);

  k_xw<<<dim3(N_NODES / 64, D / 64), 256, 0, stream>>>(x, W, XW);
  k_deg<<<NE / 256, 256, 0, stream>>>(ei, deg);
  k_scan<<<1, 256, 0, stream>>>(deg, rs, dinv);
  k_fill<<<NE / 256, 256, 0, stream>>>(ei, ei + NE, rs, cur, ecol, eeid);
  k_agg<<<N_NODES, 256, 0, stream>>>(XW, b, deg, rs, ecol, eeid, dinv, out_h, sq);

  // XW dead -> reuse as bf16 hi/lo arrays (exact fit: N*D*2B*2 = N*D*4B)
  unsigned short* hhi = (unsigned short*)XW;
  unsigned short* hlo = hhi + (size_t)N_NODES * D;
  k_split<<<(N_NODES * D) / 256, 256, 0, stream>>>(out_h, hhi, hlo);
  k_gemm<<<dim3(NBLK, NBLK), 256, 0, stream>>>(hhi, hlo, sq, q, temp, candv, candi);
  k_cmerge1<<<(N_NODES * 8) / 256, 256, 0, stream>>>(candv, candi, pv8, pi8);
  k_cmerge2<<<N_NODES / 256, 256, 0, stream>>>(pv8, pi8, fv8, fi8);
  k_exact<<<N_NODES / 4, 256, 0, stream>>>(fi8, out_h, sq, q, temp,
                                           out_idx, out_rows, out_vals);
}

// Round 18
// 1032.452 us; speedup vs baseline: 4.0968x; 1.2565x over previous
//
#include <hip/hip_runtime.h>
#include <hip/hip_bf16.h>

#define N_NODES 12288
#define D 256
#define NE 196608
#define TOPK 4
#define NBLK 96          // 12288 / 128 col-blocks
#define MAXDEG 256
// MEASURED (rounds 0-9): harness reads d_out as FLOAT32, identity layout:
// [ h 3145728 | top_idx 49152 | rows 49152 | top_vals 49152 ].

typedef __attribute__((ext_vector_type(8))) short bf8;     // 8 bf16 (4 VGPR)
typedef __attribute__((ext_vector_type(4))) float f32x4;   // MFMA 16x16 acc

// ---------------- insert helpers ----------------
__device__ __forceinline__ void ins4(float v, int id, float tv[TOPK], int ti[TOPK]) {
  if (v > tv[3]) {
    tv[3] = v; ti[3] = id;
    if (tv[3] > tv[2]) {
      float a = tv[2]; tv[2] = tv[3]; tv[3] = a; int b = ti[2]; ti[2] = ti[3]; ti[3] = b;
      if (tv[2] > tv[1]) {
        float a2 = tv[1]; tv[1] = tv[2]; tv[2] = a2; int b2 = ti[1]; ti[1] = ti[2]; ti[2] = b2;
        if (tv[1] > tv[0]) {
          float a3 = tv[0]; tv[0] = tv[1]; tv[1] = a3; int b3 = ti[0]; ti[0] = ti[1]; ti[1] = b3;
        }
      }
    }
  }
}

__device__ __forceinline__ void ins4tie(float v, int id, float tv[TOPK], int ti[TOPK]) {
  if ((v > tv[3]) || (v == tv[3] && id < ti[3])) {
    tv[3] = v; ti[3] = id;
    if ((tv[3] > tv[2]) || (tv[3] == tv[2] && ti[3] < ti[2])) {
      float a = tv[2]; tv[2] = tv[3]; tv[3] = a; int b = ti[2]; ti[2] = ti[3]; ti[3] = b;
      if ((tv[2] > tv[1]) || (tv[2] == tv[1] && ti[2] < ti[1])) {
        float a2 = tv[1]; tv[1] = tv[2]; tv[2] = a2; int b2 = ti[1]; ti[1] = ti[2]; ti[2] = b2;
        if ((tv[1] > tv[0]) || (tv[1] == tv[0] && ti[1] < ti[0])) {
          float a3 = tv[0]; tv[0] = tv[1]; tv[1] = a3; int b3 = ti[0]; ti[0] = ti[1]; ti[1] = b3;
        }
      }
    }
  }
}

__device__ __forceinline__ void ins8tie(float v, int id, float tv[8], int ti8[8]) {
  if (!((v > tv[7]) || (v == tv[7] && id < ti8[7]))) return;
  tv[7] = v; ti8[7] = id;
#pragma unroll
  for (int k = 7; k > 0; --k) {
    bool sw = (tv[k] > tv[k - 1]) || (tv[k] == tv[k - 1] && ti8[k] < ti8[k - 1]);
    if (sw) {
      float a = tv[k - 1]; tv[k - 1] = tv[k]; tv[k] = a;
      int b = ti8[k - 1]; ti8[k - 1] = ti8[k]; ti8[k] = b;
    }
  }
}

// ---------------- K1: XW = x @ W ----------------
__global__ __launch_bounds__(256) void k_xw(const float* __restrict__ X,
                                            const float* __restrict__ W,
                                            float* __restrict__ XW) {
  __shared__ float sA[16][65];
  __shared__ float sB[16][65];
  const int tid = threadIdx.x;
  const int ty = tid >> 4, tx = tid & 15;
  const int by = blockIdx.x, bx = blockIdx.y;
  float acc[4][4] = {};
  for (int kk = 0; kk < D; kk += 16) {
    {
      int m = tid >> 2;
      int kq = (tid & 3) << 2;
      const float4 av = *(const float4*)&X[(size_t)(by * 64 + m) * D + kk + kq];
      sA[kq + 0][m] = av.x; sA[kq + 1][m] = av.y; sA[kq + 2][m] = av.z; sA[kq + 3][m] = av.w;
    }
    {
      int r = tid >> 4;
      int c = (tid & 15) << 2;
      const float4 bv = *(const float4*)&W[(size_t)(kk + r) * D + bx * 64 + c];
      sB[r][c + 0] = bv.x; sB[r][c + 1] = bv.y; sB[r][c + 2] = bv.z; sB[r][c + 3] = bv.w;
    }
    __syncthreads();
#pragma unroll
    for (int k = 0; k < 16; ++k) {
      float a[4], b[4];
#pragma unroll
      for (int i = 0; i < 4; i++) a[i] = sA[k][ty + 16 * i];
#pragma unroll
      for (int j = 0; j < 4; j++) b[j] = sB[k][tx + 16 * j];
#pragma unroll
      for (int i = 0; i < 4; i++)
#pragma unroll
        for (int j = 0; j < 4; j++) acc[i][j] = fmaf(a[i], b[j], acc[i][j]);
    }
    __syncthreads();
  }
#pragma unroll
  for (int i = 0; i < 4; i++)
#pragma unroll
    for (int j = 0; j < 4; j++)
      XW[(size_t)(by * 64 + ty + 16 * i) * D + bx * 64 + tx + 16 * j] = acc[i][j];
}

// ---------------- K2: in-degree histogram ----------------
__global__ void k_deg(const int* __restrict__ row, int* __restrict__ deg) {
  int e = blockIdx.x * blockDim.x + threadIdx.x;
  if (e < NE) {
    unsigned r = (unsigned)row[e];
    if (r < N_NODES) atomicAdd(&deg[r], 1);
  }
}

// ---------------- K3: exclusive scan + dinv ----------------
__global__ __launch_bounds__(256) void k_scan(const int* __restrict__ deg,
                                              int* __restrict__ row_start,
                                              float* __restrict__ dinv) {
  __shared__ int part[256];
  const int tid = threadIdx.x;
  const int L = N_NODES / 256;  // 48
  const int base = tid * L;
  int s = 0;
  for (int i = 0; i < L; i++) s += deg[base + i];
  part[tid] = s;
  __syncthreads();
  for (int off = 1; off < 256; off <<= 1) {
    int v = (tid >= off) ? part[tid - off] : 0;
    __syncthreads();
    part[tid] += v;
    __syncthreads();
  }
  int run = part[tid] - s;
  for (int i = 0; i < L; i++) {
    int d = deg[base + i];
    row_start[base + i] = run;
    dinv[base + i] = 1.0f / sqrtf((float)(d + 1));
    run += d;
  }
}

// ---------------- K4: CSR fill ----------------
__global__ void k_fill(const int* __restrict__ row, const int* __restrict__ col,
                       const int* __restrict__ row_start, int* __restrict__ cursor,
                       int* __restrict__ ecol, int* __restrict__ eeid) {
  int e = blockIdx.x * blockDim.x + threadIdx.x;
  if (e >= NE) return;
  unsigned r = (unsigned)row[e];
  if (r >= N_NODES) return;
  int p = atomicAdd(&cursor[r], 1);
  int slot = row_start[r] + p;
  if ((unsigned)slot >= NE) return;
  unsigned c = (unsigned)col[e];
  if (c >= N_NODES) c = 0;
  ecol[slot] = (int)c;
  eeid[slot] = e;
}

// ---------------- K5: aggregation (eid-sorted -> deterministic); h -> d_out ------
__global__ __launch_bounds__(256) void k_agg(const float* __restrict__ XW,
                                             const float* __restrict__ bias,
                                             const int* __restrict__ deg,
                                             const int* __restrict__ row_start,
                                             const int* __restrict__ ecol,
                                             const int* __restrict__ eeid,
                                             const float* __restrict__ dinv,
                                             float* __restrict__ h_out,
                                             float* __restrict__ sq) {
  __shared__ int sc[MAXDEG];
  __shared__ int se[MAXDEG];
  __shared__ float snorm[MAXDEG];
  __shared__ float red[256];
  const int i = blockIdx.x;
  const int tid = threadIdx.x;
  int cnt = deg[i];
  if (cnt > MAXDEG) cnt = MAXDEG;
  if (cnt < 0) cnt = 0;
  const int st = row_start[i];
  for (int t = tid; t < cnt; t += 256) {
    unsigned cc = (unsigned)ecol[st + t];
    sc[t] = (cc < N_NODES) ? (int)cc : 0;
    se[t] = eeid[st + t];
  }
  __syncthreads();
  if (tid == 0) {  // insertion sort by original edge id
    for (int a = 1; a < cnt; ++a) {
      int ce = se[a], cc = sc[a];
      int bp = a - 1;
      while (bp >= 0 && se[bp] > ce) { se[bp + 1] = se[bp]; sc[bp + 1] = sc[bp]; --bp; }
      se[bp + 1] = ce; sc[bp + 1] = cc;
    }
  }
  __syncthreads();
  const float di = dinv[i];
  for (int t = tid; t < cnt; t += 256) snorm[t] = __fmul_rn(di, dinv[sc[t]]);
  __syncthreads();
  float acc = 0.0f;
  for (int t = 0; t < cnt; ++t) {
    float v = XW[(size_t)sc[t] * D + tid];
    acc = __fadd_rn(acc, __fmul_rn(v, snorm[t]));
  }
  acc = __fadd_rn(acc, __fmul_rn(XW[(size_t)i * D + tid], __fmul_rn(di, di)));  // self loop last
  acc = __fadd_rn(acc, bias[tid]);
  h_out[(size_t)i * D + tid] = acc;
  red[tid] = __fmul_rn(acc, acc);
  __syncthreads();
  for (int off = 128; off > 0; off >>= 1) {
    if (tid < off) red[tid] = __fadd_rn(red[tid], red[tid + off]);
    __syncthreads();
  }
  if (tid == 0) sq[i] = red[0];
}

// ---------------- K6: h -> (hi, lo) bf16 split ----------------
__global__ __launch_bounds__(256) void k_split(const float* __restrict__ h,
                                               unsigned short* __restrict__ hhi,
                                               unsigned short* __restrict__ hlo) {
  int i = blockIdx.x * 256 + threadIdx.x;  // grid = N*D/256
  float v = h[i];
  __hip_bfloat16 bh = __float2bfloat16(v);
  float hiF = __bfloat162float(bh);
  __hip_bfloat16 bl = __float2bfloat16(v - hiF);
  hhi[i] = *(unsigned short*)&bh;
  hlo[i] = *(unsigned short*)&bl;
}

// ---------------- K7 v2: MFMA GEMM, frags DIRECT FROM GLOBAL (no staging) -------
// r17 diagnosis: MfmaUtil 8.6% (MFMA = 95 us of 1100); the rest was staging
// machinery (2 barriers/chunk + stage VALU) and an 8-way bank conflict in the
// scan read (stride 132: bank = rw*4+i). v2: fragments are 16B contiguous ->
// load straight from global (L2-resident panels); K-loop has ZERO barriers so
// chunk k+1 loads pipeline under chunk k MFMAs. LDS keeps only the lq dump,
// padded 132->133 (bank = rw*5+i, coprime -> 2-way pairs = free).
__global__ __launch_bounds__(256, 2) void k_gemm(const unsigned short* __restrict__ hhi,
                                                 const unsigned short* __restrict__ hlo,
                                                 const float* __restrict__ sq,
                                                 const float* __restrict__ q,
                                                 const float* __restrict__ tempP,
                                                 float* __restrict__ candv,
                                                 int* __restrict__ candi) {
  __shared__ float lqs[128][133];   // 68.1 KB -> 2 blocks/CU
  const int tid = threadIdx.x;
  const int w = tid >> 6, l = tid & 63;
  const int row0 = blockIdx.x * 128, col0 = blockIdx.y * 128;
  const float T = tempP[0];

  f32x4 acc[4][4];
#pragma unroll
  for (int a = 0; a < 4; ++a)
#pragma unroll
    for (int b = 0; b < 4; ++b) acc[a][b] = (f32x4){0.f, 0.f, 0.f, 0.f};

  // per-thread fragment base addresses (constant across K-chunks)
  const int koct = l >> 4;                       // k-octet 0..3 (8 bf16 each)
  const int arow = row0 + (w & 1) * 64 + (l & 15);
  const int brow = col0 + (w >> 1) * 64 + (l & 15);
  const unsigned short* Ah0 = hhi + (size_t)arow * D + koct * 8;
  const unsigned short* Al0 = hlo + (size_t)arow * D + koct * 8;
  const unsigned short* Bh0 = hhi + (size_t)brow * D + koct * 8;
  const unsigned short* Bl0 = hlo + (size_t)brow * D + koct * 8;

  for (int kc = 0; kc < D; kc += 32) {  // 8 K-chunks, no barriers
    bf8 Ah[4], Al[4], Bh[4], Bl[4];
#pragma unroll
    for (int a = 0; a < 4; ++a) {
      Ah[a] = *(const bf8*)(Ah0 + (size_t)a * 16 * D + kc);
      Al[a] = *(const bf8*)(Al0 + (size_t)a * 16 * D + kc);
      Bh[a] = *(const bf8*)(Bh0 + (size_t)a * 16 * D + kc);
      Bl[a] = *(const bf8*)(Bl0 + (size_t)a * 16 * D + kc);
    }
#pragma unroll
    for (int a = 0; a < 4; ++a)
#pragma unroll
      for (int b = 0; b < 4; ++b) {
        acc[a][b] = __builtin_amdgcn_mfma_f32_16x16x32_bf16(Ah[a], Bh[b], acc[a][b], 0, 0, 0);
        acc[a][b] = __builtin_amdgcn_mfma_f32_16x16x32_bf16(Ah[a], Bl[b], acc[a][b], 0, 0, 0);
        acc[a][b] = __builtin_amdgcn_mfma_f32_16x16x32_bf16(Al[a], Bh[b], acc[a][b], 0, 0, 0);
      }
  }

  // epilogue: approx lq -> LDS (C/D map: col=lane&15, row=(lane>>4)*4+reg)
#pragma unroll
  for (int a = 0; a < 4; ++a)
#pragma unroll
    for (int b = 0; b < 4; ++b)
#pragma unroll
      for (int r = 0; r < 4; ++r) {
        int rowblk = (w & 1) * 64 + a * 16 + (l >> 4) * 4 + r;
        int colblk = (w >> 1) * 64 + b * 16 + (l & 15);
        int grow = row0 + rowblk, gcol = col0 + colblk;
        float dot = acc[a][b][r];
        float d2 = fmaxf((sq[grow] + sq[gcol]) - 2.0f * dot, 0.0f);
        float gg = logf(-logf(q[(size_t)grow * N_NODES + gcol] + 1e-8f));
        lqs[rowblk][colblk] = -T * d2 - gg;
      }
  __syncthreads();
  // per-row approx top-4 over this block's 128 cols (snapshot pair-merge)
  {
    int rw = tid >> 1, cbase = (tid & 1) * 64;
    float tv[TOPK]; int ti4[TOPK];
#pragma unroll
    for (int k = 0; k < TOPK; ++k) { tv[k] = -3.0e38f; ti4[k] = 0; }
    for (int i = 0; i < 64; ++i) ins4(lqs[rw][cbase + i], col0 + cbase + i, tv, ti4);
    float ov[TOPK]; int oi[TOPK];
#pragma unroll
    for (int k = 0; k < TOPK; ++k) {
      ov[k] = __shfl_xor(tv[k], 1);
      oi[k] = __shfl_xor(ti4[k], 1);
    }
#pragma unroll
    for (int k = 0; k < TOPK; ++k) ins4tie(ov[k], oi[k], tv, ti4);
    if ((tid & 1) == 0) {
      size_t base = ((size_t)(row0 + rw) * NBLK + blockIdx.y) * TOPK;
#pragma unroll
      for (int k = 0; k < TOPK; ++k) { candv[base + k] = tv[k]; candi[base + k] = ti4[k]; }
    }
  }
}

// ---------------- K8a: per-(row, chunk-of-48) serial top-8 (pure TLP) ----------
__global__ __launch_bounds__(256) void k_cmerge1(const float* __restrict__ candv,
                                                 const int* __restrict__ candi,
                                                 float* __restrict__ pv8,
                                                 int* __restrict__ pi8) {
  int gid = blockIdx.x * 256 + threadIdx.x;      // [0, 12288*8)
  int row = gid >> 3, chunk = gid & 7;
  size_t base = (size_t)row * (NBLK * TOPK) + chunk * 48;
  float tv[8]; int ti8[8];
#pragma unroll
  for (int k = 0; k < 8; ++k) { tv[k] = -3.0e38f; ti8[k] = 0; }
  for (int i = 0; i < 48; ++i) ins8tie(candv[base + i], candi[base + i], tv, ti8);
  size_t ob = (size_t)gid * 8;
#pragma unroll
  for (int k = 0; k < 8; ++k) { pv8[ob + k] = tv[k]; pi8[ob + k] = ti8[k]; }
}

// ---------------- K8b: per-row merge of 8 partials + self-sentinel -------------
__global__ __launch_bounds__(256) void k_cmerge2(const float* __restrict__ pv8,
                                                 const int* __restrict__ pi8,
                                                 float* __restrict__ fv8,
                                                 int* __restrict__ fi8) {
  int row = blockIdx.x * 256 + threadIdx.x;      // [0, 12288)
  size_t base = (size_t)row * 64;
  float tv[8]; int ti8[8];
#pragma unroll
  for (int k = 0; k < 8; ++k) { tv[k] = -3.0e38f; ti8[k] = 0; }
  for (int i = 0; i < 64; ++i) ins8tie(pv8[base + i], pi8[base + i], tv, ti8);
  ins8tie(3.0e38f, row, tv, ti8);                // self-sentinel
  size_t ob = (size_t)row * 8;
#pragma unroll
  for (int k = 0; k < 8; ++k) { fv8[ob + k] = tv[k]; fi8[ob + k] = ti8[k]; }
}

// ---------------- K8c: exact fp32 rerank of final 8 (one wave per row) ---------
__global__ __launch_bounds__(256) void k_exact(const int* __restrict__ fi8,
                                               const float* __restrict__ h,
                                               const float* __restrict__ sq,
                                               const float* __restrict__ q,
                                               const float* __restrict__ tempP,
                                               float* __restrict__ out_idx,
                                               float* __restrict__ out_rows,
                                               float* __restrict__ out_vals) {
  const int tid = threadIdx.x;
  const int row = blockIdx.x * 4 + (tid >> 6);
  const int l = tid & 63;
  const float T = tempP[0];
  int ti8[8];
#pragma unroll
  for (int k = 0; k < 8; ++k) ti8[k] = fi8[(size_t)row * 8 + k];
  float4 hr = *(const float4*)&h[(size_t)row * D + l * 4];
  float lqe[8];
#pragma unroll
  for (int k = 0; k < 8; ++k) {
    int c = ti8[k];
    float4 hc = *(const float4*)&h[(size_t)c * D + l * 4];
    float p = fmaf(hr.x, hc.x, 0.0f);
    p = fmaf(hr.y, hc.y, p);
    p = fmaf(hr.z, hc.z, p);
    p = fmaf(hr.w, hc.w, p);
#pragma unroll
    for (int m = 1; m < 64; m <<= 1) p += __shfl_xor(p, m);
    float d2 = fmaxf(__fsub_rn(__fadd_rn(sq[row], sq[c]), __fmul_rn(2.0f, p)), 0.0f);
    float lp = -__fmul_rn(T, d2);
    float gg = logf(-logf(__fadd_rn(q[(size_t)row * N_NODES + c], 1e-8f)));
    lqe[k] = __fsub_rn(lp, gg);
  }
  float bv[TOPK]; int bi[TOPK];
#pragma unroll
  for (int k = 0; k < TOPK; ++k) { bv[k] = -3.0e38f; bi[k] = 0; }
#pragma unroll
  for (int k = 0; k < 8; ++k) {   // dedupe guard (sentinel + organic self)
    bool dup = false;
#pragma unroll
    for (int k2 = 0; k2 < 8; ++k2)
      if (k2 < k) dup = dup || (ti8[k2] == ti8[k]);
    if (!dup) ins4tie(lqe[k], ti8[k], bv, bi);
  }
  if (l == 0) {
#pragma unroll
    for (int k = 0; k < TOPK; ++k) {
      out_idx[(size_t)row * TOPK + k] = (float)bi[k];
      out_rows[(size_t)row * TOPK + k] = (float)row;
      out_vals[(size_t)row * TOPK + k] = bv[k];
    }
  }
}

// ---------------- launcher ----------------
extern "C" void kernel_launch(void* const* d_in, const int* in_sizes, int n_in,
                              void* d_out, int out_size, void* d_ws, size_t ws_size,
                              hipStream_t stream) {
  const float* x = nullptr;     // 3145728
  const float* W = nullptr;     // 65536
  const float* b = nullptr;     // 256
  const float* temp = nullptr;  // 1
  const float* q = nullptr;     // 150994944
  const int* ei = nullptr;      // 393216
  for (int i = 0; i < n_in; ++i) {
    switch (in_sizes[i]) {
      case 3145728:   x = (const float*)d_in[i]; break;
      case 65536:     W = (const float*)d_in[i]; break;
      case 256:       b = (const float*)d_in[i]; break;
      case 1:         temp = (const float*)d_in[i]; break;
      case 150994944: q = (const float*)d_in[i]; break;
      case 393216:    ei = (const int*)d_in[i]; break;
      default: break;
    }
  }
  if (!x || !W || !b || !temp || !q || !ei) return;

  float* out = (float*)d_out;
  float* out_h = out;                                  // [0, 3145728)
  float* out_idx = out + (size_t)N_NODES * D;          // [3145728, 3194880)
  float* out_rows = out_idx + (size_t)N_NODES * TOPK;  // [3194880, 3244032)
  float* out_vals = out_rows + (size_t)N_NODES * TOPK; // [3244032, 3293184)

  char* ws = (char*)d_ws;
  size_t off = 0;
  auto alloc = [&](size_t bytes) {
    char* p = ws + off;
    off += (bytes + 255) & ~(size_t)255;
    return p;
  };
  float* XW = (float*)alloc((size_t)N_NODES * D * 4);  // reused as hhi/hlo after k_agg
  int* deg = (int*)alloc((size_t)N_NODES * 4);
  int* rs = (int*)alloc((size_t)N_NODES * 4);
  int* cur = (int*)alloc((size_t)N_NODES * 4);
  float* dinv = (float*)alloc((size_t)N_NODES * 4);
  float* sq = (float*)alloc((size_t)N_NODES * 4);
  int* ecol = (int*)alloc((size_t)NE * 4);
  int* eeid = (int*)alloc((size_t)NE * 4);
  float* candv = (float*)alloc((size_t)N_NODES * NBLK * TOPK * 4);  // 18.9 MB
  int* candi = (int*)alloc((size_t)N_NODES * NBLK * TOPK * 4);      // 18.9 MB
  float* pv8 = (float*)alloc((size_t)N_NODES * 64 * 4);             // 3.1 MB
  int* pi8 = (int*)alloc((size_t)N_NODES * 64 * 4);                 // 3.1 MB
  float* fv8 = (float*)alloc((size_t)N_NODES * 8 * 4);              // 0.4 MB
  int* fi8 = (int*)alloc((size_t)N_NODES * 8 * 4);                  // 0.4 MB
  if (off > ws_size) return;  // loud zero-output beacon if ws too small

  hipMemsetAsync(deg, 0, (size_t)N_NODES * 4, stream);
  hipMemsetAsync(cur, 0, (size_t)N_NODES * 4, stream);

  k_xw<<<dim3(N_NODES / 64, D / 64), 256, 0, stream>>>(x, W, XW);
  k_deg<<<NE / 256, 256, 0, stream>>>(ei, deg);
  k_scan<<<1, 256, 0, stream>>>(deg, rs, dinv);
  k_fill<<<NE / 256, 256, 0, stream>>>(ei, ei + NE, rs, cur, ecol, eeid);
  k_agg<<<N_NODES, 256, 0, stream>>>(XW, b, deg, rs, ecol, eeid, dinv, out_h, sq);

  // XW dead -> reuse as bf16 hi/lo arrays (exact fit: N*D*2B*2 = N*D*4B)
  unsigned short* hhi = (unsigned short*)XW;
  unsigned short* hlo = hhi + (size_t)N_NODES * D;
  k_split<<<(N_NODES * D) / 256, 256, 0, stream>>>(out_h, hhi, hlo);
  k_gemm<<<dim3(NBLK, NBLK), 256, 0, stream>>>(hhi, hlo, sq, q, temp, candv, candi);
  k_cmerge1<<<(N_NODES * 8) / 256, 256, 0, stream>>>(candv, candi, pv8, pi8);
  k_cmerge2<<<N_NODES / 256, 256, 0, stream>>>(pv8, pi8, fv8, fi8);
  k_exact<<<N_NODES / 4, 256, 0, stream>>>(fi8, out_h, sq, q, temp,
                                           out_idx, out_rows, out_vals);
}